// Round 1
// baseline (804.766 us; speedup 1.0000x reference)
//
#include <hip/hip_runtime.h>

// ---------------------------------------------------------------------------
// GraphSAGE VAE forward, f32 baseline.
// N=50000 nodes, E=800000 edges, IN=256, HID=128, OUT=64, BN_EPS=1e-5.
//
// Restructure:
//   layer1: Y1 = x @ [W1l|W1r]  (N x 256); x1 = bn(relu(agg(Y1[:, :128])/deg + b1 + Y1[:,128:]))
//   layer2: a2 = agg(x1)/deg;   x2 = bn(relu([a2|x1] @ [[W2l];[W2r]] + b2))
//   layer3: Y3 = x2 @ [W3l|W3r]; mz = agg(Y3[:, :128])/deg + b3 + Y3[:,128:]
//           z  = mz[:, :64] + exp(mz[:,64:]) * mean(eps, axis=0)
//   dec:    h  = bn(relu(z @ Wd1 + bd1)) + x1;  out = h @ Wd2 + bd2
// Aggregations all width-128 via CSR (no f32 atomics).
// ---------------------------------------------------------------------------

constexpr float BN_EPS = 1e-5f;

// ---------------- CSR construction ----------------

__global__ void hist_kernel(const int* __restrict__ dst, int E, int* __restrict__ deg) {
    int e = blockIdx.x * 256 + threadIdx.x;
    if (e < E) atomicAdd(&deg[dst[e]], 1);
}

__global__ __launch_bounds__(1024)
void scan_kernel(const int* __restrict__ deg, int N, int E,
                 int* __restrict__ row_ptr, int* __restrict__ cursor,
                 float* __restrict__ inv_deg) {
    __shared__ int sd[1024];
    int t = threadIdx.x;
    int chunk = (N + 1023) / 1024;
    int b = t * chunk;
    int e = min(b + chunk, N);
    int s = 0;
    for (int i = b; i < e; i++) s += deg[i];
    sd[t] = s;
    __syncthreads();
    for (int off = 1; off < 1024; off <<= 1) {
        int v = (t >= off) ? sd[t - off] : 0;
        __syncthreads();
        sd[t] += v;
        __syncthreads();
    }
    int excl = sd[t] - s;
    int base = excl;
    for (int i = b; i < e; i++) {
        int d = deg[i];
        row_ptr[i] = base;
        cursor[i]  = base;
        inv_deg[i] = 1.0f / (float)max(d, 1);
        base += d;
    }
    if (t == 0) row_ptr[N] = E;
}

__global__ void fill_kernel(const int* __restrict__ src, const int* __restrict__ dst,
                            int E, int* __restrict__ cursor, int* __restrict__ csr) {
    int e = blockIdx.x * 256 + threadIdx.x;
    if (e < E) {
        int p = atomicAdd(&cursor[dst[e]], 1);
        csr[p] = src[e];
    }
}

// ---------------- weight packing ----------------

// B[k][c] = c<128 ? Wl[k][c] : Wr[k][c-128]   (Wl,Wr are Kx128; B is Kx256)
__global__ void pack_lr(const float* __restrict__ Wl, const float* __restrict__ Wr,
                        float* __restrict__ B) {
    int idx = blockIdx.x * 256 + threadIdx.x;  // 256*256
    int k = idx >> 8, c = idx & 255;
    B[idx] = (c < 128) ? Wl[k * 128 + c] : Wr[k * 128 + (c - 128)];
}

// B[k][c] = k<128 ? Wt[k][c] : Wb[k-128][c]   (Wt,Wb are 128x256; B is 256x256)
__global__ void pack_tb(const float* __restrict__ Wt, const float* __restrict__ Wb,
                        float* __restrict__ B) {
    int idx = blockIdx.x * 256 + threadIdx.x;
    int k = idx >> 8, c = idx & 255;
    B[idx] = (k < 128) ? Wt[k * 256 + c] : Wb[(k - 128) * 256 + c];
}

// ---------------- eps mean over T=10 ----------------

__global__ void epsmean_kernel(const float* __restrict__ eps, float* __restrict__ em, int N) {
    int idx = blockIdx.x * 256 + threadIdx.x;   // N*16 float4 slots
    if (idx >= N * 16) return;
    const float4* p = (const float4*)eps;
    float4 s = make_float4(0.f, 0.f, 0.f, 0.f);
    int i = idx >> 4, q = idx & 15;
    for (int t = 0; t < 10; t++) {
        float4 v = p[(size_t)(t * N + i) * 16 + q];
        s.x += v.x; s.y += v.y; s.z += v.z; s.w += v.w;
    }
    float4 o = make_float4(s.x * 0.1f, s.y * 0.1f, s.z * 0.1f, s.w * 0.1f);
    ((float4*)em)[(size_t)i * 16 + q] = o;
}

// ---------------- f32 GEMM: C(MxNC) = A(MxK) @ B(KxNC) + epilogue ----------------

template<int K, int NC, bool BIAS, bool BNRELU, bool SKIP>
__global__ __launch_bounds__(256)
void gemm_kernel(const float* __restrict__ A, const float* __restrict__ B,
                 const float* __restrict__ bias, const float* __restrict__ gamma,
                 const float* __restrict__ beta,
                 const float* __restrict__ skip, int skip_ld, int skip_off,
                 float* __restrict__ C, int M) {
    __shared__ float As[16][64];   // [k][row]
    __shared__ float Bs[16][64];   // [k][col]
    const int tid = threadIdx.x;
    const int tx = tid & 15;       // col group (4 cols)
    const int ty = tid >> 4;       // row group (4 rows)
    const int row0 = blockIdx.x * 64;
    const int col0 = blockIdx.y * 64;

    const int ar  = tid >> 2;      // A-load: tile row 0..63
    const int akq = tid & 3;       // A-load: which float4 of 16 k
    const int bk  = tid >> 4;      // B-load: k 0..15
    const int bc4 = tid & 15;      // B-load: float4 col 0..15

    float acc[4][4] = {};
    const int aRow = row0 + ar;

    for (int k0 = 0; k0 < K; k0 += 16) {
        float4 av = make_float4(0.f, 0.f, 0.f, 0.f);
        if (aRow < M) av = *(const float4*)&A[(size_t)aRow * K + k0 + 4 * akq];
        float4 bv = *(const float4*)&B[(size_t)(k0 + bk) * NC + col0 + 4 * bc4];
        __syncthreads();
        As[4 * akq + 0][ar] = av.x;
        As[4 * akq + 1][ar] = av.y;
        As[4 * akq + 2][ar] = av.z;
        As[4 * akq + 3][ar] = av.w;
        *(float4*)&Bs[bk][4 * bc4] = bv;
        __syncthreads();
        #pragma unroll
        for (int kk = 0; kk < 16; kk++) {
            const float4 a4 = *(const float4*)&As[kk][4 * ty];
            const float4 b4 = *(const float4*)&Bs[kk][4 * tx];
            const float avv[4] = {a4.x, a4.y, a4.z, a4.w};
            const float bvv[4] = {b4.x, b4.y, b4.z, b4.w};
            #pragma unroll
            for (int i = 0; i < 4; i++)
                #pragma unroll
                for (int j = 0; j < 4; j++)
                    acc[i][j] = fmaf(avv[i], bvv[j], acc[i][j]);
        }
    }

    const float rs = rsqrtf(1.0f + BN_EPS);
    const int colb = col0 + 4 * tx;
    #pragma unroll
    for (int i = 0; i < 4; i++) {
        int row = row0 + 4 * ty + i;
        if (row >= M) continue;
        float4 o;
        float* v = &o.x;
        #pragma unroll
        for (int j = 0; j < 4; j++) {
            float xv = acc[i][j];
            if (BIAS)   xv += bias[colb + j];
            if (BNRELU) { xv = fmaxf(xv, 0.f); xv = xv * (gamma[colb + j] * rs) + beta[colb + j]; }
            if (SKIP)   xv += skip[(size_t)row * skip_ld + skip_off + colb + j];
            v[j] = xv;
        }
        *(float4*)&C[(size_t)row * NC + colb] = o;
    }
}

// ---------------- aggregation kernels (width 128) ----------------

// x1 = bn(relu(agg(Y1[:, :128])/deg + b1 + Y1[:,128:]))  -> catX[:,128:]
__global__ __launch_bounds__(128)
void agg1_kernel(const float* __restrict__ Y1, const int* __restrict__ row_ptr,
                 const int* __restrict__ csr, const float* __restrict__ inv_deg,
                 const float* __restrict__ b1, const float* __restrict__ g1,
                 const float* __restrict__ be1, float* __restrict__ catX) {
    int i = blockIdx.x, c = threadIdx.x;
    int b = row_ptr[i], e = row_ptr[i + 1];
    float s = 0.f;
    int ee = b;
    for (; ee + 1 < e; ee += 2) {
        int s0 = csr[ee], s1 = csr[ee + 1];
        s += Y1[(size_t)s0 * 256 + c] + Y1[(size_t)s1 * 256 + c];
    }
    if (ee < e) s += Y1[(size_t)csr[ee] * 256 + c];
    float v = s * inv_deg[i] + b1[c] + Y1[(size_t)i * 256 + 128 + c];
    v = fmaxf(v, 0.f);
    v = v * (g1[c] * rsqrtf(1.0f + BN_EPS)) + be1[c];
    catX[(size_t)i * 256 + 128 + c] = v;
}

// a2 = agg(x1)/deg  (x1 lives in catX[:,128:]) -> catX[:, :128]
__global__ __launch_bounds__(128)
void agg2_kernel(const int* __restrict__ row_ptr, const int* __restrict__ csr,
                 const float* __restrict__ inv_deg, float* __restrict__ catX) {
    int i = blockIdx.x, c = threadIdx.x;
    int b = row_ptr[i], e = row_ptr[i + 1];
    float s = 0.f;
    int ee = b;
    for (; ee + 1 < e; ee += 2) {
        int s0 = csr[ee], s1 = csr[ee + 1];
        s += catX[(size_t)s0 * 256 + 128 + c] + catX[(size_t)s1 * 256 + 128 + c];
    }
    if (ee < e) s += catX[(size_t)csr[ee] * 256 + 128 + c];
    catX[(size_t)i * 256 + c] = s * inv_deg[i];
}

// mz = agg(Y3[:, :128])/deg + b3 + Y3[:,128:];  z = mz[:, :64] + exp(mz[:,64:])*em
__global__ __launch_bounds__(128)
void agg3_kernel(const float* __restrict__ Y3, const int* __restrict__ row_ptr,
                 const int* __restrict__ csr, const float* __restrict__ inv_deg,
                 const float* __restrict__ b3, const float* __restrict__ em,
                 float* __restrict__ z) {
    __shared__ float mz[128];
    int i = blockIdx.x, c = threadIdx.x;
    int b = row_ptr[i], e = row_ptr[i + 1];
    float s = 0.f;
    int ee = b;
    for (; ee + 1 < e; ee += 2) {
        int s0 = csr[ee], s1 = csr[ee + 1];
        s += Y3[(size_t)s0 * 256 + c] + Y3[(size_t)s1 * 256 + c];
    }
    if (ee < e) s += Y3[(size_t)csr[ee] * 256 + c];
    float v = s * inv_deg[i] + b3[c] + Y3[(size_t)i * 256 + 128 + c];
    mz[c] = v;
    __syncthreads();
    if (c < 64) {
        z[(size_t)i * 64 + c] = mz[c] + expf(mz[64 + c]) * em[(size_t)i * 64 + c];
    }
}

// ---------------- launch ----------------

extern "C" void kernel_launch(void* const* d_in, const int* in_sizes, int n_in,
                              void* d_out, int out_size, void* d_ws, size_t ws_size,
                              hipStream_t stream) {
    const float* x    = (const float*)d_in[0];
    const int*   ei   = (const int*)d_in[1];
    const float* eps  = (const float*)d_in[2];
    const float* W1l  = (const float*)d_in[3];
    const float* b1   = (const float*)d_in[4];
    const float* W1r  = (const float*)d_in[5];
    const float* g1   = (const float*)d_in[6];
    const float* be1  = (const float*)d_in[7];
    const float* W2l  = (const float*)d_in[8];
    const float* b2   = (const float*)d_in[9];
    const float* W2r  = (const float*)d_in[10];
    const float* g2   = (const float*)d_in[11];
    const float* be2  = (const float*)d_in[12];
    const float* W3l  = (const float*)d_in[13];
    const float* b3   = (const float*)d_in[14];
    const float* W3r  = (const float*)d_in[15];
    const float* Wd1  = (const float*)d_in[16];
    const float* bd1  = (const float*)d_in[17];
    const float* g3   = (const float*)d_in[18];
    const float* be3  = (const float*)d_in[19];
    const float* Wd2  = (const float*)d_in[20];
    const float* bd2  = (const float*)d_in[21];

    const int Nn = in_sizes[0] / 256;      // 50000
    const int E  = in_sizes[1] / 2;        // 800000
    const int* srcp = ei;
    const int* dstp = ei + E;

    // workspace carve-up
    char* w = (char*)d_ws;
    auto alloc = [&](size_t bytes) -> void* {
        void* p = (void*)w;
        w += (bytes + 255) & ~(size_t)255;
        return p;
    };
    int*   deg     = (int*)  alloc((size_t)Nn * 4);
    int*   row_ptr = (int*)  alloc((size_t)(Nn + 1) * 4);
    int*   cursor  = (int*)  alloc((size_t)Nn * 4);
    float* inv_deg = (float*)alloc((size_t)Nn * 4);
    int*   csr     = (int*)  alloc((size_t)E * 4);
    float* B1      = (float*)alloc(256 * 256 * 4);
    float* B2      = (float*)alloc(256 * 256 * 4);
    float* B3      = (float*)alloc(256 * 256 * 4);
    float* em      = (float*)alloc((size_t)Nn * 64 * 4);
    float* z       = (float*)alloc((size_t)Nn * 64 * 4);
    float* bufA    = (float*)alloc((size_t)Nn * 256 * 4);  // Y1, then x2
    float* bufB    = (float*)alloc((size_t)Nn * 256 * 4);  // catX = [a2 | x1]
    float* bufC    = (float*)alloc((size_t)Nn * 256 * 4);  // Y3, then h
    if ((size_t)(w - (char*)d_ws) > ws_size) return;  // insufficient workspace

    hipMemsetAsync(deg, 0, (size_t)Nn * 4, stream);
    hist_kernel<<<(E + 255) / 256, 256, 0, stream>>>(dstp, E, deg);
    scan_kernel<<<1, 1024, 0, stream>>>(deg, Nn, E, row_ptr, cursor, inv_deg);
    fill_kernel<<<(E + 255) / 256, 256, 0, stream>>>(srcp, dstp, E, cursor, csr);
    pack_lr<<<256, 256, 0, stream>>>(W1l, W1r, B1);
    pack_tb<<<256, 256, 0, stream>>>(W2l, W2r, B2);
    pack_lr<<<256, 256, 0, stream>>>(W3l, W3r, B3);
    epsmean_kernel<<<(Nn * 16 + 255) / 256, 256, 0, stream>>>(eps, em, Nn);

    dim3 g4((Nn + 63) / 64, 4);
    dim3 g2d((Nn + 63) / 64, 2);

    // layer 1: Y1 = x @ [W1l|W1r]
    gemm_kernel<256, 256, false, false, false><<<g4, 256, 0, stream>>>(
        x, B1, nullptr, nullptr, nullptr, nullptr, 0, 0, bufA, Nn);
    agg1_kernel<<<Nn, 128, 0, stream>>>(bufA, row_ptr, csr, inv_deg, b1, g1, be1, bufB);
    // layer 2
    agg2_kernel<<<Nn, 128, 0, stream>>>(row_ptr, csr, inv_deg, bufB);
    gemm_kernel<256, 256, true, true, false><<<g4, 256, 0, stream>>>(
        bufB, B2, b2, g2, be2, nullptr, 0, 0, bufA, Nn);
    // layer 3
    gemm_kernel<256, 256, false, false, false><<<g4, 256, 0, stream>>>(
        bufA, B3, nullptr, nullptr, nullptr, nullptr, 0, 0, bufC, Nn);
    agg3_kernel<<<Nn, 128, 0, stream>>>(bufC, row_ptr, csr, inv_deg, b3, em, z);
    // decoder
    gemm_kernel<64, 128, true, true, true><<<g2d, 256, 0, stream>>>(
        z, Wd1, bd1, g3, be3, /*skip=*/bufB, 256, 128, bufC, Nn);
    gemm_kernel<128, 256, true, false, false><<<g4, 256, 0, stream>>>(
        bufC, Wd2, bd2, nullptr, nullptr, nullptr, 0, 0, (float*)d_out, Nn);
}

// Round 2
// 677.671 us; speedup vs baseline: 1.1875x; 1.1875x over previous
//
#include <hip/hip_runtime.h>

// ---------------------------------------------------------------------------
// GraphSAGE VAE forward, f32. Round 2: multi-block CSR scan + 128x64 GEMM tile.
//
//   layer1: Y1 = x @ [W1l|W1r]  (N x 256); x1 = bn(relu(agg(Y1[:, :128])/deg + b1 + Y1[:,128:]))
//   layer2: a2 = agg(x1)/deg;   x2 = bn(relu([a2|x1] @ [[W2l];[W2r]] + b2))
//   layer3: Y3 = x2 @ [W3l|W3r]; mz = agg(Y3[:, :128])/deg + b3 + Y3[:,128:]
//           z  = mz[:, :64] + exp(mz[:,64:]) * mean(eps, axis=0)
//   dec:    h  = bn(relu(z @ Wd1 + bd1)) + x1;  out = h @ Wd2 + bd2
// ---------------------------------------------------------------------------

constexpr float BN_EPS = 1e-5f;

// ---------------- CSR construction ----------------

__global__ void hist_kernel(const int* __restrict__ dst, int E, int* __restrict__ deg) {
    int e = blockIdx.x * 256 + threadIdx.x;
    if (e < E) atomicAdd(&deg[dst[e]], 1);
}

// pass A: per-block sums of deg
__global__ __launch_bounds__(256)
void scan_partial(const int* __restrict__ deg, int N, int* __restrict__ bsum) {
    __shared__ int sd[256];
    int i = blockIdx.x * 256 + threadIdx.x;
    int v = (i < N) ? deg[i] : 0;
    sd[threadIdx.x] = v;
    __syncthreads();
    for (int off = 128; off > 0; off >>= 1) {
        if (threadIdx.x < off) sd[threadIdx.x] += sd[threadIdx.x + off];
        __syncthreads();
    }
    if (threadIdx.x == 0) bsum[blockIdx.x] = sd[0];
}

// pass B: single small block scans the block sums (nb <= 1024) -> exclusive
__global__ __launch_bounds__(1024)
void scan_bsum(int* __restrict__ bsum, int nb) {
    __shared__ int sd[1024];
    int t = threadIdx.x;
    int v = (t < nb) ? bsum[t] : 0;
    sd[t] = v;
    __syncthreads();
    for (int off = 1; off < 1024; off <<= 1) {
        int u = (t >= off) ? sd[t - off] : 0;
        __syncthreads();
        sd[t] += u;
        __syncthreads();
    }
    if (t < nb) bsum[t] = sd[t] - v;   // exclusive
}

// pass C: per-block exclusive scan + coalesced writes of row_ptr/cursor/inv_deg
__global__ __launch_bounds__(256)
void scan_final(const int* __restrict__ deg, const int* __restrict__ bsum, int N, int E,
                int* __restrict__ row_ptr, int* __restrict__ cursor,
                float* __restrict__ inv_deg) {
    __shared__ int sd[256];
    int i = blockIdx.x * 256 + threadIdx.x;
    int d = (i < N) ? deg[i] : 0;
    sd[threadIdx.x] = d;
    __syncthreads();
    for (int off = 1; off < 256; off <<= 1) {
        int u = (threadIdx.x >= off) ? sd[threadIdx.x - off] : 0;
        __syncthreads();
        sd[threadIdx.x] += u;
        __syncthreads();
    }
    if (i < N) {
        int excl = bsum[blockIdx.x] + sd[threadIdx.x] - d;
        row_ptr[i] = excl;
        cursor[i]  = excl;
        inv_deg[i] = 1.0f / (float)max(d, 1);
        if (i == N - 1) row_ptr[N] = E;
    }
}

__global__ void fill_kernel(const int* __restrict__ src, const int* __restrict__ dst,
                            int E, int* __restrict__ cursor, int* __restrict__ csr) {
    int e = blockIdx.x * 256 + threadIdx.x;
    if (e < E) {
        int p = atomicAdd(&cursor[dst[e]], 1);
        csr[p] = src[e];
    }
}

// ---------------- weight packing ----------------

__global__ void pack_lr(const float* __restrict__ Wl, const float* __restrict__ Wr,
                        float* __restrict__ B) {
    int idx = blockIdx.x * 256 + threadIdx.x;  // 256*256
    int k = idx >> 8, c = idx & 255;
    B[idx] = (c < 128) ? Wl[k * 128 + c] : Wr[k * 128 + (c - 128)];
}

__global__ void pack_tb(const float* __restrict__ Wt, const float* __restrict__ Wb,
                        float* __restrict__ B) {
    int idx = blockIdx.x * 256 + threadIdx.x;
    int k = idx >> 8, c = idx & 255;
    B[idx] = (k < 128) ? Wt[k * 256 + c] : Wb[(k - 128) * 256 + c];
}

// ---------------- eps mean over T=10 ----------------

__global__ void epsmean_kernel(const float* __restrict__ eps, float* __restrict__ em, int N) {
    int idx = blockIdx.x * 256 + threadIdx.x;   // N*16 float4 slots
    if (idx >= N * 16) return;
    const float4* p = (const float4*)eps;
    float4 s = make_float4(0.f, 0.f, 0.f, 0.f);
    int i = idx >> 4, q = idx & 15;
    for (int t = 0; t < 10; t++) {
        float4 v = p[(size_t)(t * N + i) * 16 + q];
        s.x += v.x; s.y += v.y; s.z += v.z; s.w += v.w;
    }
    float4 o = make_float4(s.x * 0.1f, s.y * 0.1f, s.z * 0.1f, s.w * 0.1f);
    ((float4*)em)[(size_t)i * 16 + q] = o;
}

// ---------------- f32 GEMM: C(MxNC) = A(MxK) @ B(KxNC), 128x64 tile ----------------

template<int K, int NC, bool BIAS, bool BNRELU, bool SKIP>
__global__ __launch_bounds__(256)
void gemm_kernel(const float* __restrict__ A, const float* __restrict__ B,
                 const float* __restrict__ bias, const float* __restrict__ gamma,
                 const float* __restrict__ beta,
                 const float* __restrict__ skip, int skip_ld, int skip_off,
                 float* __restrict__ C, int M) {
    __shared__ float As[16][128];  // [k][row]
    __shared__ float Bs[16][64];   // [k][col]
    const int tid = threadIdx.x;
    const int tx = tid & 15;       // col group (4 cols)
    const int ty = tid >> 4;       // row group (8 rows)
    const int row0 = blockIdx.x * 128;
    const int col0 = blockIdx.y * 64;

    const int ar = tid >> 1;       // A-load: tile row 0..127
    const int ah = tid & 1;        // A-load: k-half (8 k each)
    const int bk  = tid >> 4;      // B-load: k 0..15
    const int bc4 = tid & 15;      // B-load: float4 col 0..15

    float acc[8][4] = {};
    const int aRow = row0 + ar;

    for (int k0 = 0; k0 < K; k0 += 16) {
        float4 av0 = make_float4(0.f, 0.f, 0.f, 0.f);
        float4 av1 = make_float4(0.f, 0.f, 0.f, 0.f);
        if (aRow < M) {
            const float* ap = &A[(size_t)aRow * K + k0 + 8 * ah];
            av0 = *(const float4*)ap;
            av1 = *(const float4*)(ap + 4);
        }
        float4 bv = *(const float4*)&B[(size_t)(k0 + bk) * NC + col0 + 4 * bc4];
        __syncthreads();
        As[8 * ah + 0][ar] = av0.x;
        As[8 * ah + 1][ar] = av0.y;
        As[8 * ah + 2][ar] = av0.z;
        As[8 * ah + 3][ar] = av0.w;
        As[8 * ah + 4][ar] = av1.x;
        As[8 * ah + 5][ar] = av1.y;
        As[8 * ah + 6][ar] = av1.z;
        As[8 * ah + 7][ar] = av1.w;
        *(float4*)&Bs[bk][4 * bc4] = bv;
        __syncthreads();
        #pragma unroll
        for (int kk = 0; kk < 16; kk++) {
            const float4 a40 = *(const float4*)&As[kk][8 * ty];
            const float4 a41 = *(const float4*)&As[kk][8 * ty + 4];
            const float4 b4  = *(const float4*)&Bs[kk][4 * tx];
            const float avv[8] = {a40.x, a40.y, a40.z, a40.w, a41.x, a41.y, a41.z, a41.w};
            const float bvv[4] = {b4.x, b4.y, b4.z, b4.w};
            #pragma unroll
            for (int i = 0; i < 8; i++)
                #pragma unroll
                for (int j = 0; j < 4; j++)
                    acc[i][j] = fmaf(avv[i], bvv[j], acc[i][j]);
        }
    }

    const float rs = rsqrtf(1.0f + BN_EPS);
    const int colb = col0 + 4 * tx;
    #pragma unroll
    for (int i = 0; i < 8; i++) {
        int row = row0 + 8 * ty + i;
        if (row >= M) continue;
        float4 o;
        float* v = &o.x;
        #pragma unroll
        for (int j = 0; j < 4; j++) {
            float xv = acc[i][j];
            if (BIAS)   xv += bias[colb + j];
            if (BNRELU) { xv = fmaxf(xv, 0.f); xv = xv * (gamma[colb + j] * rs) + beta[colb + j]; }
            if (SKIP)   xv += skip[(size_t)row * skip_ld + skip_off + colb + j];
            v[j] = xv;
        }
        *(float4*)&C[(size_t)row * NC + colb] = o;
    }
}

// ---------------- aggregation kernels (width 128) ----------------

__global__ __launch_bounds__(128)
void agg1_kernel(const float* __restrict__ Y1, const int* __restrict__ row_ptr,
                 const int* __restrict__ csr, const float* __restrict__ inv_deg,
                 const float* __restrict__ b1, const float* __restrict__ g1,
                 const float* __restrict__ be1, float* __restrict__ catX) {
    int i = blockIdx.x, c = threadIdx.x;
    int b = row_ptr[i], e = row_ptr[i + 1];
    float s = 0.f;
    int ee = b;
    for (; ee + 1 < e; ee += 2) {
        int s0 = csr[ee], s1 = csr[ee + 1];
        s += Y1[(size_t)s0 * 256 + c] + Y1[(size_t)s1 * 256 + c];
    }
    if (ee < e) s += Y1[(size_t)csr[ee] * 256 + c];
    float v = s * inv_deg[i] + b1[c] + Y1[(size_t)i * 256 + 128 + c];
    v = fmaxf(v, 0.f);
    v = v * (g1[c] * rsqrtf(1.0f + BN_EPS)) + be1[c];
    catX[(size_t)i * 256 + 128 + c] = v;
}

__global__ __launch_bounds__(128)
void agg2_kernel(const int* __restrict__ row_ptr, const int* __restrict__ csr,
                 const float* __restrict__ inv_deg, float* __restrict__ catX) {
    int i = blockIdx.x, c = threadIdx.x;
    int b = row_ptr[i], e = row_ptr[i + 1];
    float s = 0.f;
    int ee = b;
    for (; ee + 1 < e; ee += 2) {
        int s0 = csr[ee], s1 = csr[ee + 1];
        s += catX[(size_t)s0 * 256 + 128 + c] + catX[(size_t)s1 * 256 + 128 + c];
    }
    if (ee < e) s += catX[(size_t)csr[ee] * 256 + 128 + c];
    catX[(size_t)i * 256 + c] = s * inv_deg[i];
}

__global__ __launch_bounds__(128)
void agg3_kernel(const float* __restrict__ Y3, const int* __restrict__ row_ptr,
                 const int* __restrict__ csr, const float* __restrict__ inv_deg,
                 const float* __restrict__ b3, const float* __restrict__ em,
                 float* __restrict__ z) {
    __shared__ float mz[128];
    int i = blockIdx.x, c = threadIdx.x;
    int b = row_ptr[i], e = row_ptr[i + 1];
    float s = 0.f;
    int ee = b;
    for (; ee + 1 < e; ee += 2) {
        int s0 = csr[ee], s1 = csr[ee + 1];
        s += Y3[(size_t)s0 * 256 + c] + Y3[(size_t)s1 * 256 + c];
    }
    if (ee < e) s += Y3[(size_t)csr[ee] * 256 + c];
    float v = s * inv_deg[i] + b3[c] + Y3[(size_t)i * 256 + 128 + c];
    mz[c] = v;
    __syncthreads();
    if (c < 64) {
        z[(size_t)i * 64 + c] = mz[c] + expf(mz[64 + c]) * em[(size_t)i * 64 + c];
    }
}

// ---------------- launch ----------------

extern "C" void kernel_launch(void* const* d_in, const int* in_sizes, int n_in,
                              void* d_out, int out_size, void* d_ws, size_t ws_size,
                              hipStream_t stream) {
    const float* x    = (const float*)d_in[0];
    const int*   ei   = (const int*)d_in[1];
    const float* eps  = (const float*)d_in[2];
    const float* W1l  = (const float*)d_in[3];
    const float* b1   = (const float*)d_in[4];
    const float* W1r  = (const float*)d_in[5];
    const float* g1   = (const float*)d_in[6];
    const float* be1  = (const float*)d_in[7];
    const float* W2l  = (const float*)d_in[8];
    const float* b2   = (const float*)d_in[9];
    const float* W2r  = (const float*)d_in[10];
    const float* g2   = (const float*)d_in[11];
    const float* be2  = (const float*)d_in[12];
    const float* W3l  = (const float*)d_in[13];
    const float* b3   = (const float*)d_in[14];
    const float* W3r  = (const float*)d_in[15];
    const float* Wd1  = (const float*)d_in[16];
    const float* bd1  = (const float*)d_in[17];
    const float* g3   = (const float*)d_in[18];
    const float* be3  = (const float*)d_in[19];
    const float* Wd2  = (const float*)d_in[20];
    const float* bd2  = (const float*)d_in[21];

    const int Nn = in_sizes[0] / 256;      // 50000
    const int E  = in_sizes[1] / 2;        // 800000
    const int* srcp = ei;
    const int* dstp = ei + E;
    const int nb = (Nn + 255) / 256;       // scan blocks (196 <= 1024)

    // workspace carve-up
    char* w = (char*)d_ws;
    auto alloc = [&](size_t bytes) -> void* {
        void* p = (void*)w;
        w += (bytes + 255) & ~(size_t)255;
        return p;
    };
    int*   deg     = (int*)  alloc((size_t)Nn * 4);
    int*   bsum    = (int*)  alloc((size_t)nb * 4);
    int*   row_ptr = (int*)  alloc((size_t)(Nn + 1) * 4);
    int*   cursor  = (int*)  alloc((size_t)Nn * 4);
    float* inv_deg = (float*)alloc((size_t)Nn * 4);
    int*   csr     = (int*)  alloc((size_t)E * 4);
    float* B1      = (float*)alloc(256 * 256 * 4);
    float* B2      = (float*)alloc(256 * 256 * 4);
    float* B3      = (float*)alloc(256 * 256 * 4);
    float* em      = (float*)alloc((size_t)Nn * 64 * 4);
    float* z       = (float*)alloc((size_t)Nn * 64 * 4);
    float* bufA    = (float*)alloc((size_t)Nn * 256 * 4);  // Y1, then x2
    float* bufB    = (float*)alloc((size_t)Nn * 256 * 4);  // catX = [a2 | x1]
    float* bufC    = (float*)alloc((size_t)Nn * 256 * 4);  // Y3, then h
    if ((size_t)(w - (char*)d_ws) > ws_size) return;  // insufficient workspace

    hipMemsetAsync(deg, 0, (size_t)Nn * 4, stream);
    hist_kernel<<<(E + 255) / 256, 256, 0, stream>>>(dstp, E, deg);
    scan_partial<<<nb, 256, 0, stream>>>(deg, Nn, bsum);
    scan_bsum<<<1, 1024, 0, stream>>>(bsum, nb);
    scan_final<<<nb, 256, 0, stream>>>(deg, bsum, Nn, E, row_ptr, cursor, inv_deg);
    fill_kernel<<<(E + 255) / 256, 256, 0, stream>>>(srcp, dstp, E, cursor, csr);
    pack_lr<<<256, 256, 0, stream>>>(W1l, W1r, B1);
    pack_tb<<<256, 256, 0, stream>>>(W2l, W2r, B2);
    pack_lr<<<256, 256, 0, stream>>>(W3l, W3r, B3);
    epsmean_kernel<<<(Nn * 16 + 255) / 256, 256, 0, stream>>>(eps, em, Nn);

    dim3 g4((Nn + 127) / 128, 4);
    dim3 g2d((Nn + 127) / 128, 2);

    // layer 1: Y1 = x @ [W1l|W1r]
    gemm_kernel<256, 256, false, false, false><<<g4, 256, 0, stream>>>(
        x, B1, nullptr, nullptr, nullptr, nullptr, 0, 0, bufA, Nn);
    agg1_kernel<<<Nn, 128, 0, stream>>>(bufA, row_ptr, csr, inv_deg, b1, g1, be1, bufB);
    // layer 2
    agg2_kernel<<<Nn, 128, 0, stream>>>(row_ptr, csr, inv_deg, bufB);
    gemm_kernel<256, 256, true, true, false><<<g4, 256, 0, stream>>>(
        bufB, B2, b2, g2, be2, nullptr, 0, 0, bufA, Nn);
    // layer 3
    gemm_kernel<256, 256, false, false, false><<<g4, 256, 0, stream>>>(
        bufA, B3, nullptr, nullptr, nullptr, nullptr, 0, 0, bufC, Nn);
    agg3_kernel<<<Nn, 128, 0, stream>>>(bufC, row_ptr, csr, inv_deg, b3, em, z);
    // decoder
    gemm_kernel<64, 128, true, true, true><<<g2d, 256, 0, stream>>>(
        z, Wd1, bd1, g3, be3, /*skip=*/bufB, 256, 128, bufC, Nn);
    gemm_kernel<128, 256, true, false, false><<<g4, 256, 0, stream>>>(
        bufC, Wd2, bd2, nullptr, nullptr, nullptr, 0, 0, (float*)d_out, Nn);
}

// Round 3
// 417.892 us; speedup vs baseline: 1.9258x; 1.6216x over previous
//
#include <hip/hip_runtime.h>

// ---------------------------------------------------------------------------
// GraphSAGE VAE forward. Round 3: bf16 MFMA GEMMs + bf16 activation pipeline.
// N=50000, E=800000, IN=256, HID=128, OUT=64. Mpad=50048 (391*128).
//
//   layer1: Y1 = x @ [W1l|W1r]; x1 = bn(relu(agg(Y1[:,:128])/deg + b1 + Y1[:,128:]))
//   layer2: a2 = agg(x1)/deg;   x2 = bn(relu([a2|x1] @ [[W2l];[W2r]] + b2))
//   layer3: Y3 = x2 @ [W3l|W3r]; mz = agg(Y3[:,:128])/deg + b3 + Y3[:,128:]
//           z  = mz[:,:64] + exp(mz[:,64:]) * mean(eps,0)
//   dec:    h  = bn(relu(z @ Wd1 + bd1)) + x1;  out = h @ Wd2 + bd2   (f32 out)
// ---------------------------------------------------------------------------

typedef unsigned short u16;
typedef short bf16x8 __attribute__((ext_vector_type(8)));
typedef float f32x4  __attribute__((ext_vector_type(4)));

constexpr float BN_EPS = 1e-5f;

__device__ __forceinline__ u16 f2bf(float f) {          // RNE f32 -> bf16
    unsigned u = __float_as_uint(f);
    return (u16)((u + 0x7FFFu + ((u >> 16) & 1u)) >> 16);
}
__device__ __forceinline__ float bf2f(u16 h) {
    return __uint_as_float(((unsigned)h) << 16);
}
__device__ __forceinline__ void gl_lds16(const void* g, void* l) {
    __builtin_amdgcn_global_load_lds(
        (const __attribute__((address_space(1))) unsigned*)g,
        (__attribute__((address_space(3))) unsigned*)l, 16, 0, 0);
}

// ---------------- CSR construction ----------------

__global__ void hist_kernel(const int* __restrict__ dst, int E, int* __restrict__ deg) {
    int e = blockIdx.x * 256 + threadIdx.x;
    if (e < E) atomicAdd(&deg[dst[e]], 1);
}

__global__ __launch_bounds__(256)
void scan_partial(const int* __restrict__ deg, int N, int* __restrict__ bsum) {
    __shared__ int sd[256];
    int i = blockIdx.x * 256 + threadIdx.x;
    int v = (i < N) ? deg[i] : 0;
    sd[threadIdx.x] = v;
    __syncthreads();
    for (int off = 128; off > 0; off >>= 1) {
        if (threadIdx.x < off) sd[threadIdx.x] += sd[threadIdx.x + off];
        __syncthreads();
    }
    if (threadIdx.x == 0) bsum[blockIdx.x] = sd[0];
}

__global__ __launch_bounds__(1024)
void scan_bsum(int* __restrict__ bsum, int nb) {
    __shared__ int sd[1024];
    int t = threadIdx.x;
    int v = (t < nb) ? bsum[t] : 0;
    sd[t] = v;
    __syncthreads();
    for (int off = 1; off < 1024; off <<= 1) {
        int u = (t >= off) ? sd[t - off] : 0;
        __syncthreads();
        sd[t] += u;
        __syncthreads();
    }
    if (t < nb) bsum[t] = sd[t] - v;   // exclusive
}

__global__ __launch_bounds__(256)
void scan_final(const int* __restrict__ deg, const int* __restrict__ bsum, int N, int E,
                int* __restrict__ row_ptr, int* __restrict__ cursor,
                float* __restrict__ inv_deg) {
    __shared__ int sd[256];
    int i = blockIdx.x * 256 + threadIdx.x;
    int d = (i < N) ? deg[i] : 0;
    sd[threadIdx.x] = d;
    __syncthreads();
    for (int off = 1; off < 256; off <<= 1) {
        int u = (threadIdx.x >= off) ? sd[threadIdx.x - off] : 0;
        __syncthreads();
        sd[threadIdx.x] += u;
        __syncthreads();
    }
    if (i < N) {
        int excl = bsum[blockIdx.x] + sd[threadIdx.x] - d;
        row_ptr[i] = excl;
        cursor[i]  = excl;
        inv_deg[i] = 1.0f / (float)max(d, 1);
        if (i == N - 1) row_ptr[N] = E;
    }
}

__global__ void fill_kernel(const int* __restrict__ src, const int* __restrict__ dst,
                            int E, int* __restrict__ cursor, int* __restrict__ csr) {
    int e = blockIdx.x * 256 + threadIdx.x;
    if (e < E) {
        int p = atomicAdd(&cursor[dst[e]], 1);
        csr[p] = src[e];
    }
}

// ---------------- weight packing (transposed, bf16): Bt[c][k] = W(k,c) ----------------

// W(k,c) = c<128 ? Wl[k*128+c] : Wr[k*128+c-128];  K=C=256
__global__ void pack_lr_t(const float* __restrict__ Wl, const float* __restrict__ Wr,
                          u16* __restrict__ Bt) {
    int idx = blockIdx.x * 256 + threadIdx.x;   // 65536
    int c = idx >> 8, k = idx & 255;
    float v = (c < 128) ? Wl[k * 128 + c] : Wr[k * 128 + (c - 128)];
    Bt[c * 256 + k] = f2bf(v);
}

// W(k,c) = k<128 ? Wt[k*256+c] : Wb[(k-128)*256+c];  K=C=256
__global__ void pack_tb_t(const float* __restrict__ Wt, const float* __restrict__ Wb,
                          u16* __restrict__ Bt) {
    int idx = blockIdx.x * 256 + threadIdx.x;
    int c = idx >> 8, k = idx & 255;
    float v = (k < 128) ? Wt[k * 256 + c] : Wb[(k - 128) * 256 + c];
    Bt[c * 256 + k] = f2bf(v);
}

// generic transpose pack: W is KxC row-major; Bt[c*K+k] = W[k*C+c]
__global__ void pack_t(const float* __restrict__ W, u16* __restrict__ Bt, int K, int C) {
    int idx = blockIdx.x * 256 + threadIdx.x;
    if (idx >= K * C) return;
    int c = idx / K, k = idx - c * K;
    Bt[c * K + k] = f2bf(W[k * C + c]);
}

// ---------------- x -> bf16 (padded rows zeroed) ----------------

__global__ void cast_x(const float* __restrict__ x, u16* __restrict__ xb, int N, int Mpad) {
    int idx = blockIdx.x * 256 + threadIdx.x;    // Mpad*64 groups of 4
    if (idx >= Mpad * 64) return;
    int row = idx >> 6, q = idx & 63;
    float4 v = make_float4(0.f, 0.f, 0.f, 0.f);
    if (row < N) v = *(const float4*)&x[(size_t)row * 256 + q * 4];
    ushort4 o;
    o.x = f2bf(v.x); o.y = f2bf(v.y); o.z = f2bf(v.z); o.w = f2bf(v.w);
    *(ushort4*)&xb[(size_t)row * 256 + q * 4] = o;
}

// ---------------- eps mean over T=10 (f32) ----------------

__global__ void epsmean_kernel(const float* __restrict__ eps, float* __restrict__ em, int N) {
    int idx = blockIdx.x * 256 + threadIdx.x;   // N*16 float4 slots
    if (idx >= N * 16) return;
    const float4* p = (const float4*)eps;
    float4 s = make_float4(0.f, 0.f, 0.f, 0.f);
    int i = idx >> 4, q = idx & 15;
    for (int t = 0; t < 10; t++) {
        float4 v = p[(size_t)(t * N + i) * 16 + q];
        s.x += v.x; s.y += v.y; s.z += v.z; s.w += v.w;
    }
    float4 o = make_float4(s.x * 0.1f, s.y * 0.1f, s.z * 0.1f, s.w * 0.1f);
    ((float4*)em)[(size_t)i * 16 + q] = o;
}

// ---------------- bf16 MFMA GEMM: C(M x NC) = A(M x K) @ Bt^T + epilogue ------------
// A row-major bf16 [Mpad][K]; Bt = B^T row-major bf16 [NC][K].
// Block: 256 thr = 4 waves (2x2), tile 128x128, BK=32, dbuf LDS, gl_lds staging.
// Source-XOR swizzle (slot ^= (r>>1)&3) keeps LDS linear, reads ~2-way conflict (free).
// EPI: 0 none; 1 bias+relu+bn; 2 bias+relu+bn+skip(bf16); 3 bias only.

template<int K, int NC, int EPI, bool F32OUT>
__global__ __launch_bounds__(256)
void mgemm(const u16* __restrict__ A, const u16* __restrict__ Bt,
           const float* __restrict__ bias, const float* __restrict__ gamma,
           const float* __restrict__ beta,
           const u16* __restrict__ skip, int skip_ld,
           void* __restrict__ Cout, int M) {
    __shared__ char lds[32768];
    char* As0 = lds;
    char* As1 = lds + 8192;
    char* Bs0 = lds + 16384;
    char* Bs1 = lds + 24576;

    const int t = threadIdx.x;
    const int l = t & 63;
    const int wave = t >> 6;
    const int wr = wave >> 1, wc = wave & 1;
    const int lr = l & 15, kg = l >> 4;
    const int row0 = blockIdx.x * 128;
    const int col0 = blockIdx.y * 128;

    f32x4 acc[4][4];
    #pragma unroll
    for (int m = 0; m < 4; m++)
        #pragma unroll
        for (int n = 0; n < 4; n++)
            #pragma unroll
            for (int r = 0; r < 4; r++) acc[m][n][r] = 0.f;

    const u16* Ab = A  + (size_t)row0 * K;
    const u16* Bb = Bt + (size_t)col0 * K;

    const int sr  = t >> 2;                       // staging row 0..63 (+64 second issue)
    const int sq  = (t & 3) ^ ((t >> 3) & 3);     // swizzled source k-slot
    auto stage = [&](const u16* g, char* lb, int k0) {
        gl_lds16(g + (size_t)sr * K + k0 + sq * 8,        lb + wave * 1024);
        gl_lds16(g + (size_t)(sr + 64) * K + k0 + sq * 8, lb + 4096 + wave * 1024);
    };

    stage(Ab, As0, 0);
    stage(Bb, Bs0, 0);
    __syncthreads();

    const int swz = (kg ^ ((lr >> 1) & 3)) << 4;  // read-side slot byte offset
    constexpr int NT = K / 32;
    for (int ks = 0; ks < NT; ks++) {
        char* Ac = (ks & 1) ? As1 : As0;
        char* Bc = (ks & 1) ? Bs1 : Bs0;
        if (ks + 1 < NT) {
            char* An = (ks & 1) ? As0 : As1;
            char* Bn = (ks & 1) ? Bs0 : Bs1;
            stage(Ab, An, (ks + 1) * 32);
            stage(Bb, Bn, (ks + 1) * 32);
        }
        bf16x8 af[4], bfr[4];
        #pragma unroll
        for (int m = 0; m < 4; m++)
            af[m] = *(const bf16x8*)(Ac + wr * 4096 + m * 1024 + lr * 64 + swz);
        #pragma unroll
        for (int n = 0; n < 4; n++)
            bfr[n] = *(const bf16x8*)(Bc + wc * 4096 + n * 1024 + lr * 64 + swz);
        #pragma unroll
        for (int m = 0; m < 4; m++)
            #pragma unroll
            for (int n = 0; n < 4; n++)
                acc[m][n] = __builtin_amdgcn_mfma_f32_16x16x32_bf16(
                    af[m], bfr[n], acc[m][n], 0, 0, 0);
        __syncthreads();
    }

    // ---- epilogue: per-wave LDS repack for coalesced stores ----
    const float rs = rsqrtf(1.0f + BN_EPS);
    const int colb = col0 + wc * 64;
    const int rowb = row0 + wr * 64;
    float bia[4], gpr[4], bet[4];
    if (EPI == 1 || EPI == 2) {
        #pragma unroll
        for (int n = 0; n < 4; n++) {
            int c = colb + n * 16 + lr;
            bia[n] = bias[c];
            gpr[n] = gamma[c] * rs;
            bet[n] = beta[c];
        }
    } else if (EPI == 3) {
        #pragma unroll
        for (int n = 0; n < 4; n++) bia[n] = bias[colb + n * 16 + lr];
    }
    __syncthreads();   // all waves done with staging LDS before repack reuse

    char* rp = lds + wave * 4096;   // per-wave 4KB region
    #pragma unroll
    for (int m = 0; m < 4; m++) {
        #pragma unroll
        for (int n = 0; n < 4; n++) {
            #pragma unroll
            for (int r = 0; r < 4; r++) {
                float v = acc[m][n][r];
                if (EPI == 1 || EPI == 2) {
                    v += bia[n];
                    v = fmaxf(v, 0.f);
                    v = v * gpr[n] + bet[n];
                }
                if (EPI == 2)
                    v += bf2f(skip[(size_t)(rowb + m * 16 + kg * 4 + r) * skip_ld
                                   + colb + n * 16 + lr]);
                if (EPI == 3) v += bia[n];
                int rl = kg * 4 + r, cl = n * 16 + lr;
                if (F32OUT) ((float*)rp)[rl * 64 + cl] = v;
                else        ((u16*)rp)[rl * 64 + cl]   = f2bf(v);
            }
        }
        if (F32OUT) {
            float* rpf = (float*)rp;
            #pragma unroll
            for (int rr = 0; rr < 4; rr++) {
                int rloc = rr * 4 + kg;
                int grow = rowb + m * 16 + rloc;
                if (grow < M) {
                    f32x4 v4 = *(f32x4*)&rpf[rloc * 64 + lr * 4];
                    *(f32x4*)((float*)Cout + (size_t)grow * NC + colb + lr * 4) = v4;
                }
            }
        } else {
            u16* rph = (u16*)rp;
            #pragma unroll
            for (int hh = 0; hh < 2; hh++) {
                int rloc = hh * 8 + (l >> 3);
                int grow = rowb + m * 16 + rloc;
                bf16x8 v8 = *(bf16x8*)&rph[rloc * 64 + (l & 7) * 8];
                *(bf16x8*)((u16*)Cout + (size_t)grow * NC + colb + (l & 7) * 8) = v8;
            }
        }
    }
}

// ---------------- aggregation kernels (width 128, bf16 in/out) ----------------

__global__ __launch_bounds__(128)
void agg1_kernel(const u16* __restrict__ Y1, const int* __restrict__ row_ptr,
                 const int* __restrict__ csr, const float* __restrict__ inv_deg,
                 const float* __restrict__ b1, const float* __restrict__ g1,
                 const float* __restrict__ be1, u16* __restrict__ catX) {
    int i = blockIdx.x, c = threadIdx.x;
    int b = row_ptr[i], e = row_ptr[i + 1];
    float s = 0.f;
    int ee = b;
    for (; ee + 1 < e; ee += 2) {
        int s0 = csr[ee], s1 = csr[ee + 1];
        s += bf2f(Y1[(size_t)s0 * 256 + c]) + bf2f(Y1[(size_t)s1 * 256 + c]);
    }
    if (ee < e) s += bf2f(Y1[(size_t)csr[ee] * 256 + c]);
    float v = s * inv_deg[i] + b1[c] + bf2f(Y1[(size_t)i * 256 + 128 + c]);
    v = fmaxf(v, 0.f);
    v = v * (g1[c] * rsqrtf(1.0f + BN_EPS)) + be1[c];
    catX[(size_t)i * 256 + 128 + c] = f2bf(v);
}

__global__ __launch_bounds__(128)
void agg2_kernel(const int* __restrict__ row_ptr, const int* __restrict__ csr,
                 const float* __restrict__ inv_deg, u16* __restrict__ catX) {
    int i = blockIdx.x, c = threadIdx.x;
    int b = row_ptr[i], e = row_ptr[i + 1];
    float s = 0.f;
    int ee = b;
    for (; ee + 1 < e; ee += 2) {
        int s0 = csr[ee], s1 = csr[ee + 1];
        s += bf2f(catX[(size_t)s0 * 256 + 128 + c]) + bf2f(catX[(size_t)s1 * 256 + 128 + c]);
    }
    if (ee < e) s += bf2f(catX[(size_t)csr[ee] * 256 + 128 + c]);
    catX[(size_t)i * 256 + c] = f2bf(s * inv_deg[i]);
}

__global__ __launch_bounds__(128)
void agg3_kernel(const u16* __restrict__ Y3, const int* __restrict__ row_ptr,
                 const int* __restrict__ csr, const float* __restrict__ inv_deg,
                 const float* __restrict__ b3, const float* __restrict__ em,
                 u16* __restrict__ z) {
    __shared__ float mz[128];
    int i = blockIdx.x, c = threadIdx.x;
    int b = row_ptr[i], e = row_ptr[i + 1];
    float s = 0.f;
    int ee = b;
    for (; ee + 1 < e; ee += 2) {
        int s0 = csr[ee], s1 = csr[ee + 1];
        s += bf2f(Y3[(size_t)s0 * 256 + c]) + bf2f(Y3[(size_t)s1 * 256 + c]);
    }
    if (ee < e) s += bf2f(Y3[(size_t)csr[ee] * 256 + c]);
    mz[c] = s * inv_deg[i] + b3[c] + bf2f(Y3[(size_t)i * 256 + 128 + c]);
    __syncthreads();
    if (c < 64) {
        float zv = mz[c] + expf(mz[64 + c]) * em[(size_t)i * 64 + c];
        z[(size_t)i * 64 + c] = f2bf(zv);
    }
}

// ---------------- launch ----------------

extern "C" void kernel_launch(void* const* d_in, const int* in_sizes, int n_in,
                              void* d_out, int out_size, void* d_ws, size_t ws_size,
                              hipStream_t stream) {
    const float* x    = (const float*)d_in[0];
    const int*   ei   = (const int*)d_in[1];
    const float* eps  = (const float*)d_in[2];
    const float* W1l  = (const float*)d_in[3];
    const float* b1   = (const float*)d_in[4];
    const float* W1r  = (const float*)d_in[5];
    const float* g1   = (const float*)d_in[6];
    const float* be1  = (const float*)d_in[7];
    const float* W2l  = (const float*)d_in[8];
    const float* b2   = (const float*)d_in[9];
    const float* W2r  = (const float*)d_in[10];
    const float* g2   = (const float*)d_in[11];
    const float* be2  = (const float*)d_in[12];
    const float* W3l  = (const float*)d_in[13];
    const float* b3   = (const float*)d_in[14];
    const float* W3r  = (const float*)d_in[15];
    const float* Wd1  = (const float*)d_in[16];
    const float* bd1  = (const float*)d_in[17];
    const float* g3   = (const float*)d_in[18];
    const float* be3  = (const float*)d_in[19];
    const float* Wd2  = (const float*)d_in[20];
    const float* bd2  = (const float*)d_in[21];

    const int Nn   = in_sizes[0] / 256;       // 50000
    const int E    = in_sizes[1] / 2;         // 800000
    const int Mpad = ((Nn + 127) / 128) * 128; // 50048
    const int* srcp = ei;
    const int* dstp = ei + E;
    const int nb = (Nn + 255) / 256;          // 196

    char* w = (char*)d_ws;
    auto alloc = [&](size_t bytes) -> void* {
        void* p = (void*)w;
        w += (bytes + 255) & ~(size_t)255;
        return p;
    };
    int*   deg     = (int*)  alloc((size_t)Nn * 4);
    int*   bsum    = (int*)  alloc((size_t)nb * 4);
    int*   row_ptr = (int*)  alloc((size_t)(Nn + 1) * 4);
    int*   cursor  = (int*)  alloc((size_t)Nn * 4);
    float* inv_deg = (float*)alloc((size_t)Nn * 4);
    int*   csr     = (int*)  alloc((size_t)E * 4);
    u16*   Bt1     = (u16*)  alloc(256 * 256 * 2);
    u16*   Bt2     = (u16*)  alloc(256 * 256 * 2);
    u16*   Bt3     = (u16*)  alloc(256 * 256 * 2);
    u16*   Btd1    = (u16*)  alloc(128 * 64 * 2);
    u16*   Btd2    = (u16*)  alloc(256 * 128 * 2);
    float* em      = (float*)alloc((size_t)Nn * 64 * 4);
    u16*   xb      = (u16*)  alloc((size_t)Mpad * 256 * 2);
    u16*   zb      = (u16*)  alloc((size_t)Mpad * 64 * 2);
    u16*   bufA    = (u16*)  alloc((size_t)Mpad * 256 * 2);  // Y1b, then x2b
    u16*   bufB    = (u16*)  alloc((size_t)Mpad * 256 * 2);  // catXb = [a2 | x1]
    u16*   bufC    = (u16*)  alloc((size_t)Mpad * 256 * 2);  // Y3b, then h
    if ((size_t)(w - (char*)d_ws) > ws_size) return;

    // CSR
    hipMemsetAsync(deg, 0, (size_t)Nn * 4, stream);
    hist_kernel<<<(E + 255) / 256, 256, 0, stream>>>(dstp, E, deg);
    scan_partial<<<nb, 256, 0, stream>>>(deg, Nn, bsum);
    scan_bsum<<<1, 1024, 0, stream>>>(bsum, nb);
    scan_final<<<nb, 256, 0, stream>>>(deg, bsum, Nn, E, row_ptr, cursor, inv_deg);
    fill_kernel<<<(E + 255) / 256, 256, 0, stream>>>(srcp, dstp, E, cursor, csr);

    // weights / inputs prep
    pack_lr_t<<<256, 256, 0, stream>>>(W1l, W1r, Bt1);
    pack_tb_t<<<256, 256, 0, stream>>>(W2l, W2r, Bt2);
    pack_lr_t<<<256, 256, 0, stream>>>(W3l, W3r, Bt3);
    pack_t<<<(64 * 128 + 255) / 256, 256, 0, stream>>>(Wd1, Btd1, 64, 128);
    pack_t<<<(128 * 256 + 255) / 256, 256, 0, stream>>>(Wd2, Btd2, 128, 256);
    cast_x<<<(Mpad * 64 + 255) / 256, 256, 0, stream>>>(x, xb, Nn, Mpad);
    epsmean_kernel<<<(Nn * 16 + 255) / 256, 256, 0, stream>>>(eps, em, Nn);

    dim3 g2c(Mpad / 128, 2);
    dim3 g1c(Mpad / 128, 1);

    // layer 1
    mgemm<256, 256, 0, false><<<g2c, 256, 0, stream>>>(
        xb, Bt1, nullptr, nullptr, nullptr, nullptr, 0, bufA, Mpad);
    agg1_kernel<<<Nn, 128, 0, stream>>>(bufA, row_ptr, csr, inv_deg, b1, g1, be1, bufB);
    // layer 2
    agg2_kernel<<<Nn, 128, 0, stream>>>(row_ptr, csr, inv_deg, bufB);
    mgemm<256, 256, 1, false><<<g2c, 256, 0, stream>>>(
        bufB, Bt2, b2, g2, be2, nullptr, 0, bufA, Mpad);
    // layer 3
    mgemm<256, 256, 0, false><<<g2c, 256, 0, stream>>>(
        bufA, Bt3, nullptr, nullptr, nullptr, nullptr, 0, bufC, Mpad);
    agg3_kernel<<<Nn, 128, 0, stream>>>(bufC, row_ptr, csr, inv_deg, b3, em, zb);
    // decoder
    mgemm<64, 128, 2, false><<<g1c, 256, 0, stream>>>(
        zb, Btd1, bd1, g3, be3, /*skip=x1*/ bufB + 128, 256, bufC, Mpad);
    mgemm<128, 256, 3, true><<<g2c, 256, 0, stream>>>(
        bufC, Btd2, bd2, nullptr, nullptr, nullptr, 0, d_out, Nn);
}

// Round 4
// 319.072 us; speedup vs baseline: 2.5222x; 1.3097x over previous
//
#include <hip/hip_runtime.h>

// ---------------------------------------------------------------------------
// GraphSAGE VAE forward. Round 4: bf16 MFMA GEMMs + 16-lane-group gathers,
// epsmean fused into agg3, single pack kernel.
// N=50000, E=800000, IN=256, HID=128, OUT=64. Mpad=50048.
//
//   layer1: Y1 = x @ [W1l|W1r]; x1 = bn(relu(agg(Y1[:,:128])/deg + b1 + Y1[:,128:]))
//   layer2: a2 = agg(x1)/deg;   x2 = bn(relu([a2|x1] @ [[W2l];[W2r]] + b2))
//   layer3: Y3 = x2 @ [W3l|W3r]; mz = agg(Y3[:,:128])/deg + b3 + Y3[:,128:]
//           z  = mz[:,:64] + exp(mz[:,64:]) * mean(eps,0)
//   dec:    h  = bn(relu(z @ Wd1 + bd1)) + x1;  out = h @ Wd2 + bd2   (f32 out)
// ---------------------------------------------------------------------------

typedef unsigned short u16;
typedef short bf16x8 __attribute__((ext_vector_type(8)));
typedef float f32x4  __attribute__((ext_vector_type(4)));

constexpr float BN_EPS = 1e-5f;

__device__ __forceinline__ u16 f2bf(float f) {          // RNE f32 -> bf16
    unsigned u = __float_as_uint(f);
    return (u16)((u + 0x7FFFu + ((u >> 16) & 1u)) >> 16);
}
__device__ __forceinline__ float bf2f(u16 h) {
    return __uint_as_float(((unsigned)h) << 16);
}
__device__ __forceinline__ void gl_lds16(const void* g, void* l) {
    __builtin_amdgcn_global_load_lds(
        (const __attribute__((address_space(1))) unsigned*)g,
        (__attribute__((address_space(3))) unsigned*)l, 16, 0, 0);
}

// ---------------- CSR construction ----------------

__global__ void hist_kernel(const int* __restrict__ dst, int E, int* __restrict__ deg) {
    int e = blockIdx.x * 256 + threadIdx.x;
    if (e < E) atomicAdd(&deg[dst[e]], 1);
}

__global__ __launch_bounds__(256)
void scan_partial(const int* __restrict__ deg, int N, int* __restrict__ bsum) {
    __shared__ int sd[256];
    int i = blockIdx.x * 256 + threadIdx.x;
    int v = (i < N) ? deg[i] : 0;
    sd[threadIdx.x] = v;
    __syncthreads();
    for (int off = 128; off > 0; off >>= 1) {
        if (threadIdx.x < off) sd[threadIdx.x] += sd[threadIdx.x + off];
        __syncthreads();
    }
    if (threadIdx.x == 0) bsum[blockIdx.x] = sd[0];
}

__global__ __launch_bounds__(1024)
void scan_bsum(int* __restrict__ bsum, int nb) {
    __shared__ int sd[1024];
    int t = threadIdx.x;
    int v = (t < nb) ? bsum[t] : 0;
    sd[t] = v;
    __syncthreads();
    for (int off = 1; off < 1024; off <<= 1) {
        int u = (t >= off) ? sd[t - off] : 0;
        __syncthreads();
        sd[t] += u;
        __syncthreads();
    }
    if (t < nb) bsum[t] = sd[t] - v;   // exclusive
}

__global__ __launch_bounds__(256)
void scan_final(const int* __restrict__ deg, const int* __restrict__ bsum, int N, int E,
                int* __restrict__ row_ptr, int* __restrict__ cursor,
                float* __restrict__ inv_deg) {
    __shared__ int sd[256];
    int i = blockIdx.x * 256 + threadIdx.x;
    int d = (i < N) ? deg[i] : 0;
    sd[threadIdx.x] = d;
    __syncthreads();
    for (int off = 1; off < 256; off <<= 1) {
        int u = (threadIdx.x >= off) ? sd[threadIdx.x - off] : 0;
        __syncthreads();
        sd[threadIdx.x] += u;
        __syncthreads();
    }
    if (i < N) {
        int excl = bsum[blockIdx.x] + sd[threadIdx.x] - d;
        row_ptr[i] = excl;
        cursor[i]  = excl;
        inv_deg[i] = 1.0f / (float)max(d, 1);
        if (i == N - 1) row_ptr[N] = E;
    }
}

__global__ void fill_kernel(const int* __restrict__ src, const int* __restrict__ dst,
                            int E, int* __restrict__ cursor, int* __restrict__ csr) {
    int e = blockIdx.x * 256 + threadIdx.x;
    if (e < E) {
        int p = atomicAdd(&cursor[dst[e]], 1);
        csr[p] = src[e];
    }
}

// ---------------- all weight packs in one kernel (transposed bf16 Bt[c][k]) --------

__global__ void pack_all(const float* __restrict__ W1l, const float* __restrict__ W1r,
                         const float* __restrict__ W2l, const float* __restrict__ W2r,
                         const float* __restrict__ W3l, const float* __restrict__ W3r,
                         const float* __restrict__ Wd1, const float* __restrict__ Wd2,
                         u16* __restrict__ Bt1, u16* __restrict__ Bt2,
                         u16* __restrict__ Bt3, u16* __restrict__ Btd1,
                         u16* __restrict__ Btd2) {
    int idx = blockIdx.x * 256 + threadIdx.x;
    if (idx < 65536) {                       // Bt1: W(k,c)=c<128?W1l[k,c]:W1r[k,c-128]
        int c = idx >> 8, k = idx & 255;
        float v = (c < 128) ? W1l[k * 128 + c] : W1r[k * 128 + (c - 128)];
        Bt1[c * 256 + k] = f2bf(v);
    } else if (idx < 131072) {               // Bt2: W(k,c)=k<128?W2l[k,c]:W2r[k-128,c]
        int i2 = idx - 65536;
        int c = i2 >> 8, k = i2 & 255;
        float v = (k < 128) ? W2l[k * 256 + c] : W2r[(k - 128) * 256 + c];
        Bt2[c * 256 + k] = f2bf(v);
    } else if (idx < 196608) {               // Bt3: like Bt1 with W3
        int i2 = idx - 131072;
        int c = i2 >> 8, k = i2 & 255;
        float v = (c < 128) ? W3l[k * 128 + c] : W3r[k * 128 + (c - 128)];
        Bt3[c * 256 + k] = f2bf(v);
    } else if (idx < 204800) {               // Btd1: Wd1 is 64x128
        int i2 = idx - 196608;
        int c = i2 >> 6, k = i2 & 63;
        Btd1[i2] = f2bf(Wd1[k * 128 + c]);
    } else if (idx < 237568) {               // Btd2: Wd2 is 128x256
        int i2 = idx - 204800;
        int c = i2 >> 7, k = i2 & 127;
        Btd2[i2] = f2bf(Wd2[k * 256 + c]);
    }
}

// ---------------- x -> bf16 (padded rows zeroed) ----------------

__global__ void cast_x(const float* __restrict__ x, u16* __restrict__ xb, int N, int Mpad) {
    int idx = blockIdx.x * 256 + threadIdx.x;    // Mpad*64 groups of 4
    if (idx >= Mpad * 64) return;
    int row = idx >> 6, q = idx & 63;
    float4 v = make_float4(0.f, 0.f, 0.f, 0.f);
    if (row < N) v = *(const float4*)&x[(size_t)row * 256 + q * 4];
    ushort4 o;
    o.x = f2bf(v.x); o.y = f2bf(v.y); o.z = f2bf(v.z); o.w = f2bf(v.w);
    *(ushort4*)&xb[(size_t)row * 256 + q * 4] = o;
}

// ---------------- bf16 MFMA GEMM (unchanged from round 3) ----------------

template<int K, int NC, int EPI, bool F32OUT>
__global__ __launch_bounds__(256)
void mgemm(const u16* __restrict__ A, const u16* __restrict__ Bt,
           const float* __restrict__ bias, const float* __restrict__ gamma,
           const float* __restrict__ beta,
           const u16* __restrict__ skip, int skip_ld,
           void* __restrict__ Cout, int M) {
    __shared__ char lds[32768];
    char* As0 = lds;
    char* As1 = lds + 8192;
    char* Bs0 = lds + 16384;
    char* Bs1 = lds + 24576;

    const int t = threadIdx.x;
    const int l = t & 63;
    const int wave = t >> 6;
    const int wr = wave >> 1, wc = wave & 1;
    const int lr = l & 15, kg = l >> 4;
    const int row0 = blockIdx.x * 128;
    const int col0 = blockIdx.y * 128;

    f32x4 acc[4][4];
    #pragma unroll
    for (int m = 0; m < 4; m++)
        #pragma unroll
        for (int n = 0; n < 4; n++)
            #pragma unroll
            for (int r = 0; r < 4; r++) acc[m][n][r] = 0.f;

    const u16* Ab = A  + (size_t)row0 * K;
    const u16* Bb = Bt + (size_t)col0 * K;

    const int sr  = t >> 2;
    const int sq  = (t & 3) ^ ((t >> 3) & 3);     // swizzled source k-slot
    auto stage = [&](const u16* g, char* lb, int k0) {
        gl_lds16(g + (size_t)sr * K + k0 + sq * 8,        lb + wave * 1024);
        gl_lds16(g + (size_t)(sr + 64) * K + k0 + sq * 8, lb + 4096 + wave * 1024);
    };

    stage(Ab, As0, 0);
    stage(Bb, Bs0, 0);
    __syncthreads();

    const int swz = (kg ^ ((lr >> 1) & 3)) << 4;  // read-side slot byte offset
    constexpr int NT = K / 32;
    for (int ks = 0; ks < NT; ks++) {
        char* Ac = (ks & 1) ? As1 : As0;
        char* Bc = (ks & 1) ? Bs1 : Bs0;
        if (ks + 1 < NT) {
            char* An = (ks & 1) ? As0 : As1;
            char* Bn = (ks & 1) ? Bs0 : Bs1;
            stage(Ab, An, (ks + 1) * 32);
            stage(Bb, Bn, (ks + 1) * 32);
        }
        bf16x8 af[4], bfr[4];
        #pragma unroll
        for (int m = 0; m < 4; m++)
            af[m] = *(const bf16x8*)(Ac + wr * 4096 + m * 1024 + lr * 64 + swz);
        #pragma unroll
        for (int n = 0; n < 4; n++)
            bfr[n] = *(const bf16x8*)(Bc + wc * 4096 + n * 1024 + lr * 64 + swz);
        #pragma unroll
        for (int m = 0; m < 4; m++)
            #pragma unroll
            for (int n = 0; n < 4; n++)
                acc[m][n] = __builtin_amdgcn_mfma_f32_16x16x32_bf16(
                    af[m], bfr[n], acc[m][n], 0, 0, 0);
        __syncthreads();
    }

    // ---- epilogue: per-wave LDS repack for coalesced stores ----
    const float rs = rsqrtf(1.0f + BN_EPS);
    const int colb = col0 + wc * 64;
    const int rowb = row0 + wr * 64;
    float bia[4], gpr[4], bet[4];
    if (EPI == 1 || EPI == 2) {
        #pragma unroll
        for (int n = 0; n < 4; n++) {
            int c = colb + n * 16 + lr;
            bia[n] = bias[c];
            gpr[n] = gamma[c] * rs;
            bet[n] = beta[c];
        }
    } else if (EPI == 3) {
        #pragma unroll
        for (int n = 0; n < 4; n++) bia[n] = bias[colb + n * 16 + lr];
    }
    __syncthreads();

    char* rp = lds + wave * 4096;
    #pragma unroll
    for (int m = 0; m < 4; m++) {
        #pragma unroll
        for (int n = 0; n < 4; n++) {
            #pragma unroll
            for (int r = 0; r < 4; r++) {
                float v = acc[m][n][r];
                if (EPI == 1 || EPI == 2) {
                    v += bia[n];
                    v = fmaxf(v, 0.f);
                    v = v * gpr[n] + bet[n];
                }
                if (EPI == 2)
                    v += bf2f(skip[(size_t)(rowb + m * 16 + kg * 4 + r) * skip_ld
                                   + colb + n * 16 + lr]);
                if (EPI == 3) v += bia[n];
                int rl = kg * 4 + r, cl = n * 16 + lr;
                if (F32OUT) ((float*)rp)[rl * 64 + cl] = v;
                else        ((u16*)rp)[rl * 64 + cl]   = f2bf(v);
            }
        }
        if (F32OUT) {
            float* rpf = (float*)rp;
            #pragma unroll
            for (int rr = 0; rr < 4; rr++) {
                int rloc = rr * 4 + kg;
                int grow = rowb + m * 16 + rloc;
                if (grow < M) {
                    f32x4 v4 = *(f32x4*)&rpf[rloc * 64 + lr * 4];
                    *(f32x4*)((float*)Cout + (size_t)grow * NC + colb + lr * 4) = v4;
                }
            }
        } else {
            u16* rph = (u16*)rp;
            #pragma unroll
            for (int hh = 0; hh < 2; hh++) {
                int rloc = hh * 8 + (l >> 3);
                int grow = rowb + m * 16 + rloc;
                bf16x8 v8 = *(bf16x8*)&rph[rloc * 64 + (l & 7) * 8];
                *(bf16x8*)((u16*)Cout + (size_t)grow * NC + colb + (l & 7) * 8) = v8;
            }
        }
    }
}

// ---------------- 16-lane-group aggregation (bf16x8 gathers) ----------------
// Each 16-lane group owns one node; lane loads 8 bf16 (16B) per neighbor row.
// Block = 256 threads = 16 nodes. N=50000 = 3125 blocks exactly.

__global__ __launch_bounds__(256)
void agg1_kernel(const u16* __restrict__ Y1, const int* __restrict__ row_ptr,
                 const int* __restrict__ csr, const float* __restrict__ inv_deg,
                 const float* __restrict__ b1, const float* __restrict__ g1,
                 const float* __restrict__ be1, u16* __restrict__ catX, int N) {
    int g   = (blockIdx.x * 256 + threadIdx.x) >> 4;
    int sub = threadIdx.x & 15;
    if (g >= N) return;
    int b = row_ptr[g], e = row_ptr[g + 1];
    const int off = sub * 8;
    float a[8] = {};
    int ee = b;
    for (; ee + 1 < e; ee += 2) {
        int j0 = csr[ee], j1 = csr[ee + 1];
        bf16x8 v0 = *(const bf16x8*)&Y1[(size_t)j0 * 256 + off];
        bf16x8 v1 = *(const bf16x8*)&Y1[(size_t)j1 * 256 + off];
        #pragma unroll
        for (int r = 0; r < 8; r++)
            a[r] += bf2f((u16)v0[r]) + bf2f((u16)v1[r]);
    }
    if (ee < e) {
        bf16x8 v0 = *(const bf16x8*)&Y1[(size_t)csr[ee] * 256 + off];
        #pragma unroll
        for (int r = 0; r < 8; r++) a[r] += bf2f((u16)v0[r]);
    }
    float id = inv_deg[g];
    bf16x8 u = *(const bf16x8*)&Y1[(size_t)g * 256 + 128 + off];
    const float rs = rsqrtf(1.0f + BN_EPS);
    bf16x8 o;
    #pragma unroll
    for (int r = 0; r < 8; r++) {
        int c = off + r;
        float v = a[r] * id + b1[c] + bf2f((u16)u[r]);
        v = fmaxf(v, 0.f);
        v = v * (g1[c] * rs) + be1[c];
        o[r] = (short)f2bf(v);
    }
    *(bf16x8*)&catX[(size_t)g * 256 + 128 + off] = o;
}

__global__ __launch_bounds__(256)
void agg2_kernel(const int* __restrict__ row_ptr, const int* __restrict__ csr,
                 const float* __restrict__ inv_deg, u16* __restrict__ catX, int N) {
    int g   = (blockIdx.x * 256 + threadIdx.x) >> 4;
    int sub = threadIdx.x & 15;
    if (g >= N) return;
    int b = row_ptr[g], e = row_ptr[g + 1];
    const int off = sub * 8;
    float a[8] = {};
    int ee = b;
    for (; ee + 1 < e; ee += 2) {
        int j0 = csr[ee], j1 = csr[ee + 1];
        bf16x8 v0 = *(const bf16x8*)&catX[(size_t)j0 * 256 + 128 + off];
        bf16x8 v1 = *(const bf16x8*)&catX[(size_t)j1 * 256 + 128 + off];
        #pragma unroll
        for (int r = 0; r < 8; r++)
            a[r] += bf2f((u16)v0[r]) + bf2f((u16)v1[r]);
    }
    if (ee < e) {
        bf16x8 v0 = *(const bf16x8*)&catX[(size_t)csr[ee] * 256 + 128 + off];
        #pragma unroll
        for (int r = 0; r < 8; r++) a[r] += bf2f((u16)v0[r]);
    }
    float id = inv_deg[g];
    bf16x8 o;
    #pragma unroll
    for (int r = 0; r < 8; r++) o[r] = (short)f2bf(a[r] * id);
    *(bf16x8*)&catX[(size_t)g * 256 + off] = o;
}

// agg3 + fused eps-mean:  mz = agg(Y3[:,:128])/deg + b3 + Y3[:,128:]
//                         z  = mz[:,:64] + exp(mz[:,64:]) * mean(eps,0)
__global__ __launch_bounds__(256)
void agg3_kernel(const u16* __restrict__ Y3, const int* __restrict__ row_ptr,
                 const int* __restrict__ csr, const float* __restrict__ inv_deg,
                 const float* __restrict__ b3, const float* __restrict__ eps,
                 u16* __restrict__ z, int N) {
    int g   = (blockIdx.x * 256 + threadIdx.x) >> 4;
    int sub = threadIdx.x & 15;
    if (g >= N) return;
    int b = row_ptr[g], e = row_ptr[g + 1];
    const int off = sub * 8;

    // eps mean: lane covers channels sub*4..sub*4+3 (f32x4), sum over T=10
    f32x4 emv = {0.f, 0.f, 0.f, 0.f};
    #pragma unroll
    for (int t10 = 0; t10 < 10; t10++) {
        f32x4 v = *(const f32x4*)&eps[((size_t)t10 * N + g) * 64 + sub * 4];
        emv += v;
    }
    emv *= 0.1f;

    float a[8] = {};
    int ee = b;
    for (; ee + 1 < e; ee += 2) {
        int j0 = csr[ee], j1 = csr[ee + 1];
        bf16x8 v0 = *(const bf16x8*)&Y3[(size_t)j0 * 256 + off];
        bf16x8 v1 = *(const bf16x8*)&Y3[(size_t)j1 * 256 + off];
        #pragma unroll
        for (int r = 0; r < 8; r++)
            a[r] += bf2f((u16)v0[r]) + bf2f((u16)v1[r]);
    }
    if (ee < e) {
        bf16x8 v0 = *(const bf16x8*)&Y3[(size_t)csr[ee] * 256 + off];
        #pragma unroll
        for (int r = 0; r < 8; r++) a[r] += bf2f((u16)v0[r]);
    }
    float id = inv_deg[g];
    bf16x8 u = *(const bf16x8*)&Y3[(size_t)g * 256 + 128 + off];
    float mzv[8];
    #pragma unroll
    for (int r = 0; r < 8; r++)
        mzv[r] = a[r] * id + b3[off + r] + bf2f((u16)u[r]);

    // redistribute em: lane sub<8 needs channels sub*8..sub*8+7
    //   -> components from lanes (2*sub) and (2*sub+1) of this 16-lane group
    const int wl = threadIdx.x & 63;
    const int wb = wl & ~15;
    const int s0 = wb + ((2 * sub) & 15);
    const int s1 = wb + ((2 * sub + 1) & 15);
    float em8[8];
    #pragma unroll
    for (int q = 0; q < 4; q++) {
        em8[q]     = __shfl(emv[q], s0);
        em8[4 + q] = __shfl(emv[q], s1);
    }
    // pair mean (lanes 0..7) with log_std (lanes 8..15)
    float hi[8];
    #pragma unroll
    for (int r = 0; r < 8; r++) hi[r] = __shfl_xor(mzv[r], 8);

    if (sub < 8) {
        bf16x8 o;
        #pragma unroll
        for (int r = 0; r < 8; r++)
            o[r] = (short)f2bf(mzv[r] + expf(hi[r]) * em8[r]);
        *(bf16x8*)&z[(size_t)g * 64 + sub * 8] = o;
    }
}

// ---------------- launch ----------------

extern "C" void kernel_launch(void* const* d_in, const int* in_sizes, int n_in,
                              void* d_out, int out_size, void* d_ws, size_t ws_size,
                              hipStream_t stream) {
    const float* x    = (const float*)d_in[0];
    const int*   ei   = (const int*)d_in[1];
    const float* eps  = (const float*)d_in[2];
    const float* W1l  = (const float*)d_in[3];
    const float* b1   = (const float*)d_in[4];
    const float* W1r  = (const float*)d_in[5];
    const float* g1   = (const float*)d_in[6];
    const float* be1  = (const float*)d_in[7];
    const float* W2l  = (const float*)d_in[8];
    const float* b2   = (const float*)d_in[9];
    const float* W2r  = (const float*)d_in[10];
    const float* g2   = (const float*)d_in[11];
    const float* be2  = (const float*)d_in[12];
    const float* W3l  = (const float*)d_in[13];
    const float* b3   = (const float*)d_in[14];
    const float* W3r  = (const float*)d_in[15];
    const float* Wd1  = (const float*)d_in[16];
    const float* bd1  = (const float*)d_in[17];
    const float* g3   = (const float*)d_in[18];
    const float* be3  = (const float*)d_in[19];
    const float* Wd2  = (const float*)d_in[20];
    const float* bd2  = (const float*)d_in[21];

    const int Nn   = in_sizes[0] / 256;        // 50000
    const int E    = in_sizes[1] / 2;          // 800000
    const int Mpad = ((Nn + 127) / 128) * 128; // 50048
    const int* srcp = ei;
    const int* dstp = ei + E;
    const int nb = (Nn + 255) / 256;           // 196

    char* w = (char*)d_ws;
    auto alloc = [&](size_t bytes) -> void* {
        void* p = (void*)w;
        w += (bytes + 255) & ~(size_t)255;
        return p;
    };
    int*   deg     = (int*)  alloc((size_t)Nn * 4);
    int*   bsum    = (int*)  alloc((size_t)nb * 4);
    int*   row_ptr = (int*)  alloc((size_t)(Nn + 1) * 4);
    int*   cursor  = (int*)  alloc((size_t)Nn * 4);
    float* inv_deg = (float*)alloc((size_t)Nn * 4);
    int*   csr     = (int*)  alloc((size_t)E * 4);
    u16*   Bt1     = (u16*)  alloc(256 * 256 * 2);
    u16*   Bt2     = (u16*)  alloc(256 * 256 * 2);
    u16*   Bt3     = (u16*)  alloc(256 * 256 * 2);
    u16*   Btd1    = (u16*)  alloc(128 * 64 * 2);
    u16*   Btd2    = (u16*)  alloc(256 * 128 * 2);
    u16*   xb      = (u16*)  alloc((size_t)Mpad * 256 * 2);
    u16*   zb      = (u16*)  alloc((size_t)Mpad * 64 * 2);
    u16*   bufA    = (u16*)  alloc((size_t)Mpad * 256 * 2);  // Y1b, then x2b
    u16*   bufB    = (u16*)  alloc((size_t)Mpad * 256 * 2);  // catXb = [a2 | x1]
    u16*   bufC    = (u16*)  alloc((size_t)Mpad * 256 * 2);  // Y3b, then h
    if ((size_t)(w - (char*)d_ws) > ws_size) return;

    // CSR
    hipMemsetAsync(deg, 0, (size_t)Nn * 4, stream);
    hist_kernel<<<(E + 255) / 256, 256, 0, stream>>>(dstp, E, deg);
    scan_partial<<<nb, 256, 0, stream>>>(deg, Nn, bsum);
    scan_bsum<<<1, 1024, 0, stream>>>(bsum, nb);
    scan_final<<<nb, 256, 0, stream>>>(deg, bsum, Nn, E, row_ptr, cursor, inv_deg);
    fill_kernel<<<(E + 255) / 256, 256, 0, stream>>>(srcp, dstp, E, cursor, csr);

    // weights / inputs prep
    pack_all<<<(237568 + 255) / 256, 256, 0, stream>>>(
        W1l, W1r, W2l, W2r, W3l, W3r, Wd1, Wd2, Bt1, Bt2, Bt3, Btd1, Btd2);
    cast_x<<<(Mpad * 64 + 255) / 256, 256, 0, stream>>>(x, xb, Nn, Mpad);

    dim3 g2c(Mpad / 128, 2);
    dim3 g1c(Mpad / 128, 1);
    const int aggBlocks = (Nn + 15) / 16;   // nodes per block = 16

    // layer 1
    mgemm<256, 256, 0, false><<<g2c, 256, 0, stream>>>(
        xb, Bt1, nullptr, nullptr, nullptr, nullptr, 0, bufA, Mpad);
    agg1_kernel<<<aggBlocks, 256, 0, stream>>>(bufA, row_ptr, csr, inv_deg,
                                               b1, g1, be1, bufB, Nn);
    // layer 2
    agg2_kernel<<<aggBlocks, 256, 0, stream>>>(row_ptr, csr, inv_deg, bufB, Nn);
    mgemm<256, 256, 1, false><<<g2c, 256, 0, stream>>>(
        bufB, Bt2, b2, g2, be2, nullptr, 0, bufA, Mpad);
    // layer 3
    mgemm<256, 256, 0, false><<<g2c, 256, 0, stream>>>(
        bufA, Bt3, nullptr, nullptr, nullptr, nullptr, 0, bufC, Mpad);
    agg3_kernel<<<aggBlocks, 256, 0, stream>>>(bufC, row_ptr, csr, inv_deg,
                                               b3, eps, zb, Nn);
    // decoder
    mgemm<64, 128, 2, false><<<g1c, 256, 0, stream>>>(
        zb, Btd1, bd1, g3, be3, /*skip=x1*/ bufB + 128, 256, bufC, Mpad);
    mgemm<128, 256, 3, true><<<g2c, 256, 0, stream>>>(
        bufC, Btd2, bd2, nullptr, nullptr, nullptr, 0, d_out, Nn);
}

// Round 5
// 302.666 us; speedup vs baseline: 2.6589x; 1.0542x over previous
//
#include <hip/hip_runtime.h>

// ---------------------------------------------------------------------------
// GraphSAGE VAE forward. Round 5: fused decoder (2 GEMMs, 1 kernel),
// agg gather unroll x4, merged pack+cast, 2-kernel scan. 13 launches.
// N=50000, E=800000, IN=256, HID=128, OUT=64. Mpad=50048.
//
//   layer1: Y1 = x @ [W1l|W1r]; x1 = bn(relu(agg(Y1[:,:128])/deg + b1 + Y1[:,128:]))
//   layer2: a2 = agg(x1)/deg;   x2 = bn(relu([a2|x1] @ [[W2l];[W2r]] + b2))
//   layer3: Y3 = x2 @ [W3l|W3r]; mz = agg(Y3[:,:128])/deg + b3 + Y3[:,128:]
//           z  = mz[:,:64] + exp(mz[:,64:]) * mean(eps,0)
//   dec:    h  = bn(relu(z @ Wd1 + bd1)) + x1;  out = h @ Wd2 + bd2   (f32 out)
// ---------------------------------------------------------------------------

typedef unsigned short u16;
typedef short bf16x8 __attribute__((ext_vector_type(8)));
typedef float f32x4  __attribute__((ext_vector_type(4)));

constexpr float BN_EPS = 1e-5f;

__device__ __forceinline__ u16 f2bf(float f) {          // RNE f32 -> bf16
    unsigned u = __float_as_uint(f);
    return (u16)((u + 0x7FFFu + ((u >> 16) & 1u)) >> 16);
}
__device__ __forceinline__ float bf2f(u16 h) {
    return __uint_as_float(((unsigned)h) << 16);
}
__device__ __forceinline__ void gl_lds16(const void* g, void* l) {
    __builtin_amdgcn_global_load_lds(
        (const __attribute__((address_space(1))) unsigned*)g,
        (__attribute__((address_space(3))) unsigned*)l, 16, 0, 0);
}

// Stage a [128 rows][KS] bf16 row-major panel chunk (all 128 rows, 32 k at k0)
// into an 8KB LDS buffer in the wave-chunked layout used by the fragment reads.
// Source k-slot XOR-swizzle keeps LDS linear (rule: swizzle source + read, not dest).
template<int KS>
__device__ __forceinline__ void stage_panel(const u16* g, char* lb, int k0, int t) {
    const int sr   = t >> 2;
    const int sq   = (t & 3) ^ ((t >> 3) & 3);
    const int wave = t >> 6;
    gl_lds16(g + (size_t)sr * KS + k0 + sq * 8,        lb + wave * 1024);
    gl_lds16(g + (size_t)(sr + 64) * KS + k0 + sq * 8, lb + 4096 + wave * 1024);
}

// ---------------- CSR construction ----------------

__global__ void hist_kernel(const int* __restrict__ dst, int E, int* __restrict__ deg) {
    int e = blockIdx.x * 256 + threadIdx.x;
    if (e < E) atomicAdd(&deg[dst[e]], 1);
}

__global__ __launch_bounds__(256)
void scan_partial(const int* __restrict__ deg, int N, int* __restrict__ bsum) {
    __shared__ int sd[256];
    int i = blockIdx.x * 256 + threadIdx.x;
    int v = (i < N) ? deg[i] : 0;
    sd[threadIdx.x] = v;
    __syncthreads();
    for (int off = 128; off > 0; off >>= 1) {
        if (threadIdx.x < off) sd[threadIdx.x] += sd[threadIdx.x + off];
        __syncthreads();
    }
    if (threadIdx.x == 0) bsum[blockIdx.x] = sd[0];
}

// per-block exclusive scan; block base self-computed from raw bsum totals
__global__ __launch_bounds__(256)
void scan_final2(const int* __restrict__ deg, const int* __restrict__ bsum,
                 int N, int E, int* __restrict__ row_ptr, int* __restrict__ cursor,
                 float* __restrict__ inv_deg) {
    __shared__ int sd[256];
    int t = threadIdx.x;
    int partial = 0;
    for (int j = t; j < blockIdx.x; j += 256) partial += bsum[j];
    sd[t] = partial;
    __syncthreads();
    for (int off = 128; off > 0; off >>= 1) {
        if (t < off) sd[t] += sd[t + off];
        __syncthreads();
    }
    int base = sd[0];
    __syncthreads();
    int i = blockIdx.x * 256 + t;
    int d = (i < N) ? deg[i] : 0;
    sd[t] = d;
    __syncthreads();
    for (int off = 1; off < 256; off <<= 1) {
        int u = (t >= off) ? sd[t - off] : 0;
        __syncthreads();
        sd[t] += u;
        __syncthreads();
    }
    if (i < N) {
        int excl = base + sd[t] - d;
        row_ptr[i] = excl;
        cursor[i]  = excl;
        inv_deg[i] = 1.0f / (float)max(d, 1);
        if (i == N - 1) row_ptr[N] = E;
    }
}

__global__ void fill_kernel(const int* __restrict__ src, const int* __restrict__ dst,
                            int E, int* __restrict__ cursor, int* __restrict__ csr) {
    int e = blockIdx.x * 256 + threadIdx.x;
    if (e < E) {
        int p = atomicAdd(&cursor[dst[e]], 1);
        csr[p] = src[e];
    }
}

// ---------------- weight pack (transposed bf16 Bt[c][k]) + x cast, one kernel ------

__global__ void pack_cast(const float* __restrict__ x,
                          const float* __restrict__ W1l, const float* __restrict__ W1r,
                          const float* __restrict__ W2l, const float* __restrict__ W2r,
                          const float* __restrict__ W3l, const float* __restrict__ W3r,
                          const float* __restrict__ Wd1, const float* __restrict__ Wd2,
                          u16* __restrict__ Bt1, u16* __restrict__ Bt2,
                          u16* __restrict__ Bt3, u16* __restrict__ Btd1,
                          u16* __restrict__ Btd2, u16* __restrict__ xb,
                          int N, int Mpad) {
    int idx = blockIdx.x * 256 + threadIdx.x;
    if (idx < 65536) {                       // Bt1: W(k,c)=c<128?W1l[k,c]:W1r[k,c-128]
        int c = idx >> 8, k = idx & 255;
        float v = (c < 128) ? W1l[k * 128 + c] : W1r[k * 128 + (c - 128)];
        Bt1[c * 256 + k] = f2bf(v);
    } else if (idx < 131072) {               // Bt2: W(k,c)=k<128?W2l[k,c]:W2r[k-128,c]
        int i2 = idx - 65536;
        int c = i2 >> 8, k = i2 & 255;
        float v = (k < 128) ? W2l[k * 256 + c] : W2r[(k - 128) * 256 + c];
        Bt2[c * 256 + k] = f2bf(v);
    } else if (idx < 196608) {               // Bt3: like Bt1 with W3
        int i2 = idx - 131072;
        int c = i2 >> 8, k = i2 & 255;
        float v = (c < 128) ? W3l[k * 128 + c] : W3r[k * 128 + (c - 128)];
        Bt3[c * 256 + k] = f2bf(v);
    } else if (idx < 204800) {               // Btd1: Wd1 is 64x128
        int i2 = idx - 196608;
        int c = i2 >> 6, k = i2 & 63;
        Btd1[i2] = f2bf(Wd1[k * 128 + c]);
    } else if (idx < 237568) {               // Btd2: Wd2 is 128x256
        int i2 = idx - 204800;
        int c = i2 >> 7, k = i2 & 127;
        Btd2[i2] = f2bf(Wd2[k * 256 + c]);
    }
    if (idx < Mpad * 64) {                   // x -> bf16, padded rows zeroed
        int row = idx >> 6, q = idx & 63;
        float4 v = make_float4(0.f, 0.f, 0.f, 0.f);
        if (row < N) v = *(const float4*)&x[(size_t)row * 256 + q * 4];
        ushort4 o;
        o.x = f2bf(v.x); o.y = f2bf(v.y); o.z = f2bf(v.z); o.w = f2bf(v.w);
        *(ushort4*)&xb[(size_t)row * 256 + q * 4] = o;
    }
}

// ---------------- bf16 MFMA GEMM (validated r3/r4 structure) ----------------

template<int K, int NC, int EPI, bool F32OUT>
__global__ __launch_bounds__(256)
void mgemm(const u16* __restrict__ A, const u16* __restrict__ Bt,
           const float* __restrict__ bias, const float* __restrict__ gamma,
           const float* __restrict__ beta,
           const u16* __restrict__ skip, int skip_ld,
           void* __restrict__ Cout, int M) {
    __shared__ char lds[32768];
    char* As0 = lds;
    char* As1 = lds + 8192;
    char* Bs0 = lds + 16384;
    char* Bs1 = lds + 24576;

    const int t = threadIdx.x;
    const int l = t & 63;
    const int wave = t >> 6;
    const int wr = wave >> 1, wc = wave & 1;
    const int lr = l & 15, kg = l >> 4;
    const int row0 = blockIdx.x * 128;
    const int col0 = blockIdx.y * 128;

    f32x4 acc[4][4];
    #pragma unroll
    for (int m = 0; m < 4; m++)
        #pragma unroll
        for (int n = 0; n < 4; n++)
            #pragma unroll
            for (int r = 0; r < 4; r++) acc[m][n][r] = 0.f;

    const u16* Ab = A  + (size_t)row0 * K;
    const u16* Bb = Bt + (size_t)col0 * K;

    stage_panel<K>(Ab, As0, 0, t);
    stage_panel<K>(Bb, Bs0, 0, t);
    __syncthreads();

    const int swz = (kg ^ ((lr >> 1) & 3)) << 4;
    constexpr int NT = K / 32;
    for (int ks = 0; ks < NT; ks++) {
        char* Ac = (ks & 1) ? As1 : As0;
        char* Bc = (ks & 1) ? Bs1 : Bs0;
        if (ks + 1 < NT) {
            stage_panel<K>(Ab, (ks & 1) ? As0 : As1, (ks + 1) * 32, t);
            stage_panel<K>(Bb, (ks & 1) ? Bs0 : Bs1, (ks + 1) * 32, t);
        }
        bf16x8 af[4], bfr[4];
        #pragma unroll
        for (int m = 0; m < 4; m++)
            af[m] = *(const bf16x8*)(Ac + wr * 4096 + m * 1024 + lr * 64 + swz);
        #pragma unroll
        for (int n = 0; n < 4; n++)
            bfr[n] = *(const bf16x8*)(Bc + wc * 4096 + n * 1024 + lr * 64 + swz);
        #pragma unroll
        for (int m = 0; m < 4; m++)
            #pragma unroll
            for (int n = 0; n < 4; n++)
                acc[m][n] = __builtin_amdgcn_mfma_f32_16x16x32_bf16(
                    af[m], bfr[n], acc[m][n], 0, 0, 0);
        __syncthreads();
    }

    const float rs = rsqrtf(1.0f + BN_EPS);
    const int colb = col0 + wc * 64;
    const int rowb = row0 + wr * 64;
    float bia[4], gpr[4], bet[4];
    if (EPI == 1 || EPI == 2) {
        #pragma unroll
        for (int n = 0; n < 4; n++) {
            int c = colb + n * 16 + lr;
            bia[n] = bias[c];
            gpr[n] = gamma[c] * rs;
            bet[n] = beta[c];
        }
    } else if (EPI == 3) {
        #pragma unroll
        for (int n = 0; n < 4; n++) bia[n] = bias[colb + n * 16 + lr];
    }
    __syncthreads();

    char* rp = lds + wave * 4096;
    #pragma unroll
    for (int m = 0; m < 4; m++) {
        #pragma unroll
        for (int n = 0; n < 4; n++) {
            #pragma unroll
            for (int r = 0; r < 4; r++) {
                float v = acc[m][n][r];
                if (EPI == 1 || EPI == 2) {
                    v += bia[n];
                    v = fmaxf(v, 0.f);
                    v = v * gpr[n] + bet[n];
                }
                if (EPI == 2)
                    v += bf2f(skip[(size_t)(rowb + m * 16 + kg * 4 + r) * skip_ld
                                   + colb + n * 16 + lr]);
                if (EPI == 3) v += bia[n];
                int rl = kg * 4 + r, cl = n * 16 + lr;
                if (F32OUT) ((float*)rp)[rl * 64 + cl] = v;
                else        ((u16*)rp)[rl * 64 + cl]   = f2bf(v);
            }
        }
        if (F32OUT) {
            float* rpf = (float*)rp;
            #pragma unroll
            for (int rr = 0; rr < 4; rr++) {
                int rloc = rr * 4 + kg;
                int grow = rowb + m * 16 + rloc;
                if (grow < M) {
                    f32x4 v4 = *(f32x4*)&rpf[rloc * 64 + lr * 4];
                    *(f32x4*)((float*)Cout + (size_t)grow * NC + colb + lr * 4) = v4;
                }
            }
        } else {
            u16* rph = (u16*)rp;
            #pragma unroll
            for (int hh = 0; hh < 2; hh++) {
                int rloc = hh * 8 + (l >> 3);
                int grow = rowb + m * 16 + rloc;
                bf16x8 v8 = *(bf16x8*)&rph[rloc * 64 + (l & 7) * 8];
                *(bf16x8*)((u16*)Cout + (size_t)grow * NC + colb + (l & 7) * 8) = v8;
            }
        }
    }
}

// ---------------- fused decoder: out = (bn(relu(z@Wd1+bd1))+x1) @ Wd2 + bd2 --------
// Phase 1: 128x128 h-tile via MFMA (K=64, all operands staged once).
// h written bf16 to LDS [128][128] with slot-XOR swizzle (slot ^= row&7).
// Phase 2: h(LDS) @ Wd2 (K=128, dbuf-staged), f32 out via per-wave repack.

__global__ __launch_bounds__(256)
void dec_fused(const u16* __restrict__ zb, const u16* __restrict__ Btd1,
               const u16* __restrict__ Btd2, const float* __restrict__ bd1,
               const float* __restrict__ g3, const float* __restrict__ be3,
               const u16* __restrict__ x1, const float* __restrict__ bd2,
               float* __restrict__ out, int M) {
    __shared__ char lds[65536];
    const int t = threadIdx.x;
    const int l = t & 63;
    const int wave = t >> 6;
    const int wr = wave >> 1, wc = wave & 1;
    const int lr = l & 15, kg = l >> 4;
    const int row0 = blockIdx.x * 128;
    const float rs = rsqrtf(1.0f + BN_EPS);
    const int swz = (kg ^ ((lr >> 1) & 3)) << 4;
    char* hb = lds + 32768;

    // ---- phase 1 ----
    stage_panel<64>(zb + (size_t)row0 * 64, lds,         0, t);
    stage_panel<64>(zb + (size_t)row0 * 64, lds + 8192, 32, t);
    stage_panel<64>(Btd1, lds + 16384,  0, t);
    stage_panel<64>(Btd1, lds + 24576, 32, t);
    __syncthreads();

    f32x4 acc[4][4];
    #pragma unroll
    for (int m = 0; m < 4; m++)
        #pragma unroll
        for (int n = 0; n < 4; n++)
            #pragma unroll
            for (int r = 0; r < 4; r++) acc[m][n][r] = 0.f;

    #pragma unroll
    for (int ks = 0; ks < 2; ks++) {
        char* Ac = lds + ks * 8192;
        char* Bc = lds + 16384 + ks * 8192;
        bf16x8 af[4], bfr[4];
        #pragma unroll
        for (int m = 0; m < 4; m++)
            af[m] = *(const bf16x8*)(Ac + wr * 4096 + m * 1024 + lr * 64 + swz);
        #pragma unroll
        for (int n = 0; n < 4; n++)
            bfr[n] = *(const bf16x8*)(Bc + wc * 4096 + n * 1024 + lr * 64 + swz);
        #pragma unroll
        for (int m = 0; m < 4; m++)
            #pragma unroll
            for (int n = 0; n < 4; n++)
                acc[m][n] = __builtin_amdgcn_mfma_f32_16x16x32_bf16(
                    af[m], bfr[n], acc[m][n], 0, 0, 0);
    }

    {   // epilogue-1: bn(relu(+bd1)) + x1 -> h (bf16, LDS, swizzled)
        float bia[4], gpr[4], bet[4];
        #pragma unroll
        for (int n = 0; n < 4; n++) {
            int c = wc * 64 + n * 16 + lr;
            bia[n] = bd1[c];
            gpr[n] = g3[c] * rs;
            bet[n] = be3[c];
        }
        #pragma unroll
        for (int m = 0; m < 4; m++)
            #pragma unroll
            for (int n = 0; n < 4; n++)
                #pragma unroll
                for (int r = 0; r < 4; r++) {
                    int rl = wr * 64 + m * 16 + kg * 4 + r;
                    int cl = wc * 64 + n * 16 + lr;
                    float v = acc[m][n][r] + bia[n];
                    v = fmaxf(v, 0.f) * gpr[n] + bet[n];
                    v += bf2f(x1[(size_t)(row0 + rl) * 256 + cl]);
                    int slot = (cl >> 3) ^ (rl & 7);
                    ((u16*)(hb + rl * 256 + slot * 16))[cl & 7] = f2bf(v);
                }
    }
    __syncthreads();

    // ---- phase 2: two 128-col halves of Wd2 ----
    for (int ch = 0; ch < 2; ch++) {
        const u16* Bb2 = Btd2 + ch * 16384;
        stage_panel<128>(Bb2, lds, 0, t);
        #pragma unroll
        for (int m = 0; m < 4; m++)
            #pragma unroll
            for (int n = 0; n < 4; n++)
                #pragma unroll
                for (int r = 0; r < 4; r++) acc[m][n][r] = 0.f;
        __syncthreads();

        for (int ks = 0; ks < 4; ks++) {
            char* Bc = lds + (ks & 1) * 8192;
            if (ks + 1 < 4)
                stage_panel<128>(Bb2, lds + (((ks & 1) ^ 1) * 8192), (ks + 1) * 32, t);
            bf16x8 af[4], bfr[4];
            #pragma unroll
            for (int m = 0; m < 4; m++) {
                int row = wr * 64 + m * 16 + lr;
                int s = (ks * 4 + kg) ^ (row & 7);
                af[m] = *(const bf16x8*)(hb + row * 256 + s * 16);
            }
            #pragma unroll
            for (int n = 0; n < 4; n++)
                bfr[n] = *(const bf16x8*)(Bc + wc * 4096 + n * 1024 + lr * 64 + swz);
            #pragma unroll
            for (int m = 0; m < 4; m++)
                #pragma unroll
                for (int n = 0; n < 4; n++)
                    acc[m][n] = __builtin_amdgcn_mfma_f32_16x16x32_bf16(
                        af[m], bfr[n], acc[m][n], 0, 0, 0);
            __syncthreads();
        }

        // epilogue-2: +bd2, f32 coalesced stores via per-wave repack
        const int colb = ch * 128 + wc * 64;
        const int rowb = row0 + wr * 64;
        float b2v[4];
        #pragma unroll
        for (int n = 0; n < 4; n++) b2v[n] = bd2[colb + n * 16 + lr];
        char* rp = lds + wave * 4096;
        #pragma unroll
        for (int m = 0; m < 4; m++) {
            #pragma unroll
            for (int n = 0; n < 4; n++)
                #pragma unroll
                for (int r = 0; r < 4; r++)
                    ((float*)rp)[(kg * 4 + r) * 64 + n * 16 + lr] = acc[m][n][r] + b2v[n];
            float* rpf = (float*)rp;
            #pragma unroll
            for (int rr = 0; rr < 4; rr++) {
                int rloc = rr * 4 + kg;
                int grow = rowb + m * 16 + rloc;
                if (grow < M) {
                    f32x4 v4 = *(f32x4*)&rpf[rloc * 64 + lr * 4];
                    *(f32x4*)&out[(size_t)grow * 256 + colb + lr * 4] = v4;
                }
            }
        }
        __syncthreads();   // rp / staging LDS reused next ch
    }
}

// ---------------- 16-lane-group aggregation (bf16x8 gathers, unroll x4) -----------

__global__ __launch_bounds__(256)
void agg1_kernel(const u16* __restrict__ Y1, const int* __restrict__ row_ptr,
                 const int* __restrict__ csr, const float* __restrict__ inv_deg,
                 const float* __restrict__ b1, const float* __restrict__ g1,
                 const float* __restrict__ be1, u16* __restrict__ catX, int N) {
    int g   = (blockIdx.x * 256 + threadIdx.x) >> 4;
    int sub = threadIdx.x & 15;
    if (g >= N) return;
    int b = row_ptr[g], e = row_ptr[g + 1];
    const int off = sub * 8;
    float a[8] = {};
    int ee = b;
    for (; ee + 3 < e; ee += 4) {
        int j0 = csr[ee], j1 = csr[ee + 1], j2 = csr[ee + 2], j3 = csr[ee + 3];
        bf16x8 v0 = *(const bf16x8*)&Y1[(size_t)j0 * 256 + off];
        bf16x8 v1 = *(const bf16x8*)&Y1[(size_t)j1 * 256 + off];
        bf16x8 v2 = *(const bf16x8*)&Y1[(size_t)j2 * 256 + off];
        bf16x8 v3 = *(const bf16x8*)&Y1[(size_t)j3 * 256 + off];
        #pragma unroll
        for (int r = 0; r < 8; r++)
            a[r] += (bf2f((u16)v0[r]) + bf2f((u16)v1[r]))
                  + (bf2f((u16)v2[r]) + bf2f((u16)v3[r]));
    }
    for (; ee < e; ee++) {
        bf16x8 v0 = *(const bf16x8*)&Y1[(size_t)csr[ee] * 256 + off];
        #pragma unroll
        for (int r = 0; r < 8; r++) a[r] += bf2f((u16)v0[r]);
    }
    float id = inv_deg[g];
    bf16x8 u = *(const bf16x8*)&Y1[(size_t)g * 256 + 128 + off];
    const float rs = rsqrtf(1.0f + BN_EPS);
    bf16x8 o;
    #pragma unroll
    for (int r = 0; r < 8; r++) {
        int c = off + r;
        float v = a[r] * id + b1[c] + bf2f((u16)u[r]);
        v = fmaxf(v, 0.f);
        v = v * (g1[c] * rs) + be1[c];
        o[r] = (short)f2bf(v);
    }
    *(bf16x8*)&catX[(size_t)g * 256 + 128 + off] = o;
}

__global__ __launch_bounds__(256)
void agg2_kernel(const int* __restrict__ row_ptr, const int* __restrict__ csr,
                 const float* __restrict__ inv_deg, u16* __restrict__ catX, int N) {
    int g   = (blockIdx.x * 256 + threadIdx.x) >> 4;
    int sub = threadIdx.x & 15;
    if (g >= N) return;
    int b = row_ptr[g], e = row_ptr[g + 1];
    const int off = sub * 8;
    float a[8] = {};
    int ee = b;
    for (; ee + 3 < e; ee += 4) {
        int j0 = csr[ee], j1 = csr[ee + 1], j2 = csr[ee + 2], j3 = csr[ee + 3];
        bf16x8 v0 = *(const bf16x8*)&catX[(size_t)j0 * 256 + 128 + off];
        bf16x8 v1 = *(const bf16x8*)&catX[(size_t)j1 * 256 + 128 + off];
        bf16x8 v2 = *(const bf16x8*)&catX[(size_t)j2 * 256 + 128 + off];
        bf16x8 v3 = *(const bf16x8*)&catX[(size_t)j3 * 256 + 128 + off];
        #pragma unroll
        for (int r = 0; r < 8; r++)
            a[r] += (bf2f((u16)v0[r]) + bf2f((u16)v1[r]))
                  + (bf2f((u16)v2[r]) + bf2f((u16)v3[r]));
    }
    for (; ee < e; ee++) {
        bf16x8 v0 = *(const bf16x8*)&catX[(size_t)csr[ee] * 256 + 128 + off];
        #pragma unroll
        for (int r = 0; r < 8; r++) a[r] += bf2f((u16)v0[r]);
    }
    float id = inv_deg[g];
    bf16x8 o;
    #pragma unroll
    for (int r = 0; r < 8; r++) o[r] = (short)f2bf(a[r] * id);
    *(bf16x8*)&catX[(size_t)g * 256 + off] = o;
}

__global__ __launch_bounds__(256)
void agg3_kernel(const u16* __restrict__ Y3, const int* __restrict__ row_ptr,
                 const int* __restrict__ csr, const float* __restrict__ inv_deg,
                 const float* __restrict__ b3, const float* __restrict__ eps,
                 u16* __restrict__ z, int N) {
    int g   = (blockIdx.x * 256 + threadIdx.x) >> 4;
    int sub = threadIdx.x & 15;
    if (g >= N) return;
    int b = row_ptr[g], e = row_ptr[g + 1];
    const int off = sub * 8;

    // eps mean: lane covers channels sub*4..sub*4+3 (f32x4), sum over T=10
    f32x4 emv = {0.f, 0.f, 0.f, 0.f};
    #pragma unroll
    for (int t10 = 0; t10 < 10; t10++) {
        f32x4 v = *(const f32x4*)&eps[((size_t)t10 * N + g) * 64 + sub * 4];
        emv += v;
    }
    emv *= 0.1f;

    float a[8] = {};
    int ee = b;
    for (; ee + 3 < e; ee += 4) {
        int j0 = csr[ee], j1 = csr[ee + 1], j2 = csr[ee + 2], j3 = csr[ee + 3];
        bf16x8 v0 = *(const bf16x8*)&Y3[(size_t)j0 * 256 + off];
        bf16x8 v1 = *(const bf16x8*)&Y3[(size_t)j1 * 256 + off];
        bf16x8 v2 = *(const bf16x8*)&Y3[(size_t)j2 * 256 + off];
        bf16x8 v3 = *(const bf16x8*)&Y3[(size_t)j3 * 256 + off];
        #pragma unroll
        for (int r = 0; r < 8; r++)
            a[r] += (bf2f((u16)v0[r]) + bf2f((u16)v1[r]))
                  + (bf2f((u16)v2[r]) + bf2f((u16)v3[r]));
    }
    for (; ee < e; ee++) {
        bf16x8 v0 = *(const bf16x8*)&Y3[(size_t)csr[ee] * 256 + off];
        #pragma unroll
        for (int r = 0; r < 8; r++) a[r] += bf2f((u16)v0[r]);
    }
    float id = inv_deg[g];
    bf16x8 u = *(const bf16x8*)&Y3[(size_t)g * 256 + 128 + off];
    float mzv[8];
    #pragma unroll
    for (int r = 0; r < 8; r++)
        mzv[r] = a[r] * id + b3[off + r] + bf2f((u16)u[r]);

    // redistribute em: lane sub<8 needs channels sub*8..sub*8+7
    const int wl = threadIdx.x & 63;
    const int wb = wl & ~15;
    const int s0 = wb + ((2 * sub) & 15);
    const int s1 = wb + ((2 * sub + 1) & 15);
    float em8[8];
    #pragma unroll
    for (int q = 0; q < 4; q++) {
        em8[q]     = __shfl(emv[q], s0);
        em8[4 + q] = __shfl(emv[q], s1);
    }
    float hi[8];
    #pragma unroll
    for (int r = 0; r < 8; r++) hi[r] = __shfl_xor(mzv[r], 8);

    if (sub < 8) {
        bf16x8 o;
        #pragma unroll
        for (int r = 0; r < 8; r++)
            o[r] = (short)f2bf(mzv[r] + expf(hi[r]) * em8[r]);
        *(bf16x8*)&z[(size_t)g * 64 + sub * 8] = o;
    }
}

// ---------------- launch ----------------

extern "C" void kernel_launch(void* const* d_in, const int* in_sizes, int n_in,
                              void* d_out, int out_size, void* d_ws, size_t ws_size,
                              hipStream_t stream) {
    const float* x    = (const float*)d_in[0];
    const int*   ei   = (const int*)d_in[1];
    const float* eps  = (const float*)d_in[2];
    const float* W1l  = (const float*)d_in[3];
    const float* b1   = (const float*)d_in[4];
    const float* W1r  = (const float*)d_in[5];
    const float* g1   = (const float*)d_in[6];
    const float* be1  = (const float*)d_in[7];
    const float* W2l  = (const float*)d_in[8];
    const float* b2   = (const float*)d_in[9];
    const float* W2r  = (const float*)d_in[10];
    const float* g2   = (const float*)d_in[11];
    const float* be2  = (const float*)d_in[12];
    const float* W3l  = (const float*)d_in[13];
    const float* b3   = (const float*)d_in[14];
    const float* W3r  = (const float*)d_in[15];
    const float* Wd1  = (const float*)d_in[16];
    const float* bd1  = (const float*)d_in[17];
    const float* g3   = (const float*)d_in[18];
    const float* be3  = (const float*)d_in[19];
    const float* Wd2  = (const float*)d_in[20];
    const float* bd2  = (const float*)d_in[21];

    const int Nn   = in_sizes[0] / 256;        // 50000
    const int E    = in_sizes[1] / 2;          // 800000
    const int Mpad = ((Nn + 127) / 128) * 128; // 50048
    const int* srcp = ei;
    const int* dstp = ei + E;
    const int nb = (Nn + 255) / 256;           // 196

    char* w = (char*)d_ws;
    auto alloc = [&](size_t bytes) -> void* {
        void* p = (void*)w;
        w += (bytes + 255) & ~(size_t)255;
        return p;
    };
    int*   deg     = (int*)  alloc((size_t)Nn * 4);
    int*   bsum    = (int*)  alloc((size_t)nb * 4);
    int*   row_ptr = (int*)  alloc((size_t)(Nn + 1) * 4);
    int*   cursor  = (int*)  alloc((size_t)Nn * 4);
    float* inv_deg = (float*)alloc((size_t)Nn * 4);
    int*   csr     = (int*)  alloc((size_t)E * 4);
    u16*   Bt1     = (u16*)  alloc(256 * 256 * 2);
    u16*   Bt2     = (u16*)  alloc(256 * 256 * 2);
    u16*   Bt3     = (u16*)  alloc(256 * 256 * 2);
    u16*   Btd1    = (u16*)  alloc(128 * 64 * 2);
    u16*   Btd2    = (u16*)  alloc(256 * 128 * 2);
    u16*   xb      = (u16*)  alloc((size_t)Mpad * 256 * 2);
    u16*   zb      = (u16*)  alloc((size_t)Mpad * 64 * 2);
    u16*   bufA    = (u16*)  alloc((size_t)Mpad * 256 * 2);  // Y1b, then x2b
    u16*   bufB    = (u16*)  alloc((size_t)Mpad * 256 * 2);  // catXb = [a2 | x1]
    u16*   bufC    = (u16*)  alloc((size_t)Mpad * 256 * 2);  // Y3b
    if ((size_t)(w - (char*)d_ws) > ws_size) return;

    // CSR
    hipMemsetAsync(deg, 0, (size_t)Nn * 4, stream);
    hist_kernel<<<(E + 255) / 256, 256, 0, stream>>>(dstp, E, deg);
    scan_partial<<<nb, 256, 0, stream>>>(deg, Nn, bsum);
    scan_final2<<<nb, 256, 0, stream>>>(deg, bsum, Nn, E, row_ptr, cursor, inv_deg);
    fill_kernel<<<(E + 255) / 256, 256, 0, stream>>>(srcp, dstp, E, cursor, csr);

    // weights / input prep (one kernel)
    pack_cast<<<(Mpad * 64 + 255) / 256, 256, 0, stream>>>(
        x, W1l, W1r, W2l, W2r, W3l, W3r, Wd1, Wd2,
        Bt1, Bt2, Bt3, Btd1, Btd2, xb, Nn, Mpad);

    dim3 g2c(Mpad / 128, 2);
    const int aggBlocks = (Nn + 15) / 16;

    // layer 1
    mgemm<256, 256, 0, false><<<g2c, 256, 0, stream>>>(
        xb, Bt1, nullptr, nullptr, nullptr, nullptr, 0, bufA, Mpad);
    agg1_kernel<<<aggBlocks, 256, 0, stream>>>(bufA, row_ptr, csr, inv_deg,
                                               b1, g1, be1, bufB, Nn);
    // layer 2
    agg2_kernel<<<aggBlocks, 256, 0, stream>>>(row_ptr, csr, inv_deg, bufB, Nn);
    mgemm<256, 256, 1, false><<<g2c, 256, 0, stream>>>(
        bufB, Bt2, b2, g2, be2, nullptr, 0, bufA, Mpad);
    // layer 3
    mgemm<256, 256, 0, false><<<g2c, 256, 0, stream>>>(
        bufA, Bt3, nullptr, nullptr, nullptr, nullptr, 0, bufC, Mpad);
    agg3_kernel<<<aggBlocks, 256, 0, stream>>>(bufC, row_ptr, csr, inv_deg,
                                               b3, eps, zb, Nn);
    // fused decoder
    dec_fused<<<Mpad / 128, 256, 0, stream>>>(
        zb, Btd1, Btd2, bd1, g3, be3, /*x1=*/bufB + 128, bd2, (float*)d_out, Nn);
}